// Round 4
// baseline (18725.587 us; speedup 1.0000x reference)
//
#include <hip/hip_runtime.h>
#include <cstdint>
#include <cstddef>

// ---------------------------------------------------------------------------
// GRU persistent kernel, round 6: fused-gate blocks (Z+R+H~x in one A-pass).
//   - 128 gate blocks own 16 cols of ALL gates; pin Wxz|Whz|Wxr|Whr slices
//     (phase A) + Wxh|Whh (H~) = 36+.. frags ~144 VGPR. One pass over the
//     A-panel feeds Z, R and the X-part of H~ simultaneously -> per-step
//     cache traffic drops 163 MB -> ~98 MB, and Z/H_new become block-local.
//   - 64 Y blocks + 64 conv blocks run inside barrier-1's arrive/wait window.
//   - per-class main loops are code-duplicated so regalloc doesn't union the
//     pinned weight sets across classes.
//   - round-5 single-detector broadcast barrier kept verbatim (proven).
// ---------------------------------------------------------------------------

#define T_ 512
#define B_ 64
#define I_ 1024
#define H_ 2048
#define NB 256
#define NTHREADS 512
#define GSTRIDE (NB * NTHREADS)

typedef __attribute__((ext_vector_type(8))) __bf16 bf16x8;
typedef __attribute__((ext_vector_type(2))) __bf16 bf16x2;
typedef __attribute__((ext_vector_type(4))) float f32x4;
typedef __attribute__((ext_vector_type(2))) float f32x2;

// ---- workspace layout (bytes) ----
// barrier region: arr = 16 counters x 64B [0..1023]; epoch word @1024.
static constexpr size_t OFF_BAR  = 0;
static constexpr size_t OFF_WXZT = 3072;
static constexpr size_t SZ_WXT   = (size_t)H_ * I_ * 2;    // 4 MiB
static constexpr size_t SZ_WHT   = (size_t)H_ * H_ * 2;    // 8 MiB
static constexpr size_t OFF_WXRT = OFF_WXZT + SZ_WXT;
static constexpr size_t OFF_WXHT = OFF_WXRT + SZ_WXT;
static constexpr size_t OFF_WHZT = OFF_WXHT + SZ_WXT;
static constexpr size_t OFF_WHRT = OFF_WHZT + SZ_WHT;
static constexpr size_t OFF_WHHT = OFF_WHRT + SZ_WHT;
static constexpr size_t OFF_WHQT = OFF_WHHT + SZ_WHT;      // N=1024,K=2048
static constexpr size_t OFF_XBF  = OFF_WHQT + SZ_WXT;
static constexpr size_t OFF_HBF  = OFF_XBF + (size_t)2 * B_ * I_ * 2;
static constexpr size_t OFF_RHBF = OFF_HBF + (size_t)2 * B_ * H_ * 2;
static constexpr size_t WS_NEEDED = OFF_RHBF + (size_t)B_ * H_ * 2;

__device__ __forceinline__ float fsigmoid(float x) { return 1.0f / (1.0f + __expf(-x)); }
__device__ __forceinline__ float ftanh(float x)    { return 2.0f / (1.0f + __expf(-2.0f * x)) - 1.0f; }

// ---- coherent (sc1 write-through) stores for cross-block data ----
__device__ __forceinline__ void cstore8(void* p, unsigned long long v) {
    __hip_atomic_store((unsigned long long*)p, v, __ATOMIC_RELAXED, __HIP_MEMORY_SCOPE_AGENT);
}
__device__ __forceinline__ void cstore4(void* p, unsigned v) {
    __hip_atomic_store((unsigned*)p, v, __ATOMIC_RELAXED, __HIP_MEMORY_SCOPE_AGENT);
}
__device__ __forceinline__ unsigned long long pack4bf(float a, float b, float c, float d) {
    union { unsigned short s[4]; unsigned long long u; } x;
    union { __bf16 b; unsigned short s; } t;
    t.b = (__bf16)a; x.s[0] = t.s;
    t.b = (__bf16)b; x.s[1] = t.s;
    t.b = (__bf16)c; x.s[2] = t.s;
    t.b = (__bf16)d; x.s[3] = t.s;
    return x.u;
}
__device__ __forceinline__ unsigned pack2bf(float a, float b) {
    union { unsigned short s[2]; unsigned u; } x;
    union { __bf16 b; unsigned short s; } t;
    t.b = (__bf16)a; x.s[0] = t.s;
    t.b = (__bf16)b; x.s[1] = t.s;
    return x.u;
}

// ---- barrier: arrive ------------------------------------------------------
__device__ __forceinline__ void bar_arrive(unsigned* arr) {
    __syncthreads();   // drains vmcnt -> this block's WT stores are globally visible
    if (threadIdx.x == 0)
        __hip_atomic_fetch_add(&arr[(blockIdx.x & 15) * 16], 1u,
                               __ATOMIC_RELAXED, __HIP_MEMORY_SCOPE_AGENT);
}

__device__ __forceinline__ void bar_arrive_fence(unsigned* arr) {
    __syncthreads();
    __threadfence();   // prologue only: flush write-back transpose stores
    if (threadIdx.x == 0)
        __hip_atomic_fetch_add(&arr[(blockIdx.x & 15) * 16], 1u,
                               __ATOMIC_RELAXED, __HIP_MEMORY_SCOPE_AGENT);
}

__device__ __forceinline__ unsigned arr_sum(unsigned* arr) {
    unsigned sum = 0;
#pragma unroll
    for (int g = 0; g < 16; ++g)
        sum += __hip_atomic_load(&arr[g * 16],
                                 __ATOMIC_RELAXED, __HIP_MEMORY_SCOPE_AGENT);
    return sum;
}

// ---- barrier: wait (detector broadcast) -----------------------------------
__device__ __forceinline__ void bar_wait(unsigned* arr, unsigned* epw, unsigned ep) {
    if (threadIdx.x == 0) {
        const unsigned want = ep * (unsigned)NB;
        if (blockIdx.x == NB - 1) {
            // sole poller of the arrival counters
            while (arr_sum(arr) < want)
                __builtin_amdgcn_s_sleep(1);
            __hip_atomic_store(epw, ep, __ATOMIC_RELAXED, __HIP_MEMORY_SCOPE_AGENT);
        } else {
            // read-only poll on one dedicated LLC line
            int spins = 0;
            for (;;) {
                if (__hip_atomic_load(epw, __ATOMIC_RELAXED,
                                      __HIP_MEMORY_SCOPE_AGENT) >= ep) break;
                if ((++spins & 2047) == 0 && arr_sum(arr) >= want) break;  // insurance
                __builtin_amdgcn_s_sleep(1);
            }
        }
        // acquire: one cache-inv so subsequent normal loads see fresh data
        (void)__hip_atomic_load(&arr[0], __ATOMIC_ACQUIRE, __HIP_MEMORY_SCOPE_AGENT);
    }
    __syncthreads();
    asm volatile("" ::: "memory");
}

// f32 (K x N row-major) -> bf16 transposed (N x K row-major), normal stores
__device__ __forceinline__ void transpose_cvt(const float* __restrict__ src,
                                              __bf16* __restrict__ dst,
                                              int K, int lgN) {
    const int N = 1 << lgN;
    const int total = K << lgN;
    for (int idx = (int)(blockIdx.x * blockDim.x + threadIdx.x); idx < total; idx += GSTRIDE) {
        int k = idx >> lgN;
        int n = idx & (N - 1);
        dst[(size_t)n * K + k] = (__bf16)src[idx];
    }
}

// ---------------------------------------------------------------------------
// GEMM pieces with REGISTER-RESIDENT B. Tile = 64 rows x 16 cols.
// Wave w, segment i covers kb = (w + i*8)*32 within A's K dim (stride ks).
// ---------------------------------------------------------------------------
template<int NSEG, int OFF, int N>
__device__ __forceinline__ void gemm_accN(const __bf16* __restrict__ A, int ks,
                                          const bf16x8 (&pbw)[N], f32x4 acc[4]) {
    static_assert(OFF + NSEG <= N, "weight frags");
    const int tid  = (int)threadIdx.x;
    const int lane = tid & 63;
    const int w    = tid >> 6;
    const int l15  = lane & 15;
    const int q8   = (lane >> 4) << 3;

    bf16x8 pa[3][4];
    auto lseg = [&](int i, int s) {
        const int kb = ((w + (i << 3)) << 5) + q8;
#pragma unroll
        for (int m = 0; m < 4; ++m)
            pa[s][m] = *(const bf16x8*)(A + (size_t)((m << 4) + l15) * ks + kb);
    };

    lseg(0, 0);
    if constexpr (NSEG > 1) lseg(1, 1);
    if constexpr (NSEG > 2) lseg(2, 2);
#pragma unroll
    for (int i = 0; i < NSEG; ++i) {
        const int s = i % 3;
#pragma unroll
        for (int m = 0; m < 4; ++m)
            acc[m] = __builtin_amdgcn_mfma_f32_16x16x32_bf16(pa[s][m], pbw[OFF + i], acc[m], 0, 0, 0);
        if (i + 3 < NSEG) lseg(i + 3, s);
    }
}

// cross-wave reduction through LDS (64x16 tile, pitch 20)
__device__ __forceinline__ void gemm_reduce(f32x4 acc[4], float* __restrict__ red,
                                            float out2[2]) {
    constexpr int RP = 20;
    const int tid  = (int)threadIdx.x;
    const int lane = tid & 63;
    const int w    = tid >> 6;
    const int l15  = lane & 15;
    const int q4   = (lane >> 4) << 2;

    if (w >= 4) {
        float* rw = red + (size_t)(w - 4) * (64 * RP);
#pragma unroll
        for (int m = 0; m < 4; ++m)
#pragma unroll
            for (int r = 0; r < 4; ++r)
                rw[((m << 4) + q4 + r) * RP + l15] = acc[m][r];
    }
    __syncthreads();
    if (w < 4) {
        float* rw = red + (size_t)w * (64 * RP);
#pragma unroll
        for (int m = 0; m < 4; ++m)
#pragma unroll
            for (int r = 0; r < 4; ++r)
                rw[((m << 4) + q4 + r) * RP + l15] += acc[m][r];
    }
    __syncthreads();
    {
        const int a = (tid >> 3) * RP + ((tid & 7) << 1);
        f32x2 s0 = *(const f32x2*)(red + a);
        f32x2 s1 = *(const f32x2*)(red + 64 * RP + a);
        f32x2 s2 = *(const f32x2*)(red + 2 * 64 * RP + a);
        f32x2 s3 = *(const f32x2*)(red + 3 * 64 * RP + a);
        f32x2 s = s0 + s1 + s2 + s3;
        out2[0] = s[0]; out2[1] = s[1];
    }
}

// ---------------------------------------------------------------------------
// Fused gate phase A: one pass over A-panel (4 X-segments + 8 H-segments)
// feeding Z, R, and the X-part of H~ (accH). 2-deep pipeline (VGPR budget).
// Double LDS reduce for Z and R with one barrier pair.
// ---------------------------------------------------------------------------
__device__ __forceinline__ void gate_phaseA(
    const __bf16* __restrict__ Xc, const __bf16* __restrict__ Hc,
    const bf16x8 (&pbZ)[12], const bf16x8 (&pbR)[12], const bf16x8 (&pbHx)[4],
    f32x4 accH[4], float* __restrict__ red, float zsum[2], float rsum[2])
{
    constexpr int RP = 20;
    const int tid  = (int)threadIdx.x;
    const int lane = tid & 63;
    const int w    = tid >> 6;
    const int l15  = lane & 15;
    const int q8   = (lane >> 4) << 3;
    const int q4   = (lane >> 4) << 2;

    f32x4 accZ[4], accR[4];
#pragma unroll
    for (int m = 0; m < 4; ++m) {
        accZ[m] = f32x4{0.f, 0.f, 0.f, 0.f};
        accR[m] = f32x4{0.f, 0.f, 0.f, 0.f};
    }

    bf16x8 pa[2][4];
    auto lseg = [&](int i, int s) {
        const bool isx = (i < 4);
        const __bf16* A = isx ? Xc : Hc;
        const int ks = isx ? I_ : H_;
        const int kb = (isx ? ((w + (i << 3)) << 5)
                            : ((w + ((i - 4) << 3)) << 5)) + q8;
#pragma unroll
        for (int m = 0; m < 4; ++m)
            pa[s][m] = *(const bf16x8*)(A + (size_t)((m << 4) + l15) * ks + kb);
    };

    lseg(0, 0); lseg(1, 1);
#pragma unroll
    for (int i = 0; i < 12; ++i) {
        const int s = i & 1;
#pragma unroll
        for (int m = 0; m < 4; ++m) {
            accZ[m] = __builtin_amdgcn_mfma_f32_16x16x32_bf16(pa[s][m], pbZ[i], accZ[m], 0, 0, 0);
            accR[m] = __builtin_amdgcn_mfma_f32_16x16x32_bf16(pa[s][m], pbR[i], accR[m], 0, 0, 0);
        }
        if (i < 4) {
#pragma unroll
            for (int m = 0; m < 4; ++m)
                accH[m] = __builtin_amdgcn_mfma_f32_16x16x32_bf16(pa[s][m], pbHx[i], accH[m], 0, 0, 0);
        }
        if (i + 2 < 12) lseg(i + 2, s);
    }

    // double cross-wave reduce (Z and R) with one barrier pair
    float* redZ = red;
    float* redR = red + 4 * 64 * RP;
    if (w >= 4) {
        float* rz = redZ + (size_t)(w - 4) * (64 * RP);
        float* rr = redR + (size_t)(w - 4) * (64 * RP);
#pragma unroll
        for (int m = 0; m < 4; ++m)
#pragma unroll
            for (int r = 0; r < 4; ++r) {
                const int a = ((m << 4) + q4 + r) * RP + l15;
                rz[a] = accZ[m][r];
                rr[a] = accR[m][r];
            }
    }
    __syncthreads();
    if (w < 4) {
        float* rz = redZ + (size_t)w * (64 * RP);
        float* rr = redR + (size_t)w * (64 * RP);
#pragma unroll
        for (int m = 0; m < 4; ++m)
#pragma unroll
            for (int r = 0; r < 4; ++r) {
                const int a = ((m << 4) + q4 + r) * RP + l15;
                rz[a] += accZ[m][r];
                rr[a] += accR[m][r];
            }
    }
    __syncthreads();
    {
        const int a = (tid >> 3) * RP + ((tid & 7) << 1);
        f32x2 z = *(const f32x2*)(redZ + a) + *(const f32x2*)(redZ + 64 * RP + a)
                + *(const f32x2*)(redZ + 2 * 64 * RP + a) + *(const f32x2*)(redZ + 3 * 64 * RP + a);
        f32x2 r = *(const f32x2*)(redR + a) + *(const f32x2*)(redR + 64 * RP + a)
                + *(const f32x2*)(redR + 2 * 64 * RP + a) + *(const f32x2*)(redR + 3 * 64 * RP + a);
        zsum[0] = z[0]; zsum[1] = z[1];
        rsum[0] = r[0]; rsum[1] = r[1];
    }
}

__global__ __launch_bounds__(NTHREADS, 1) void gru_persistent(
    const float* __restrict__ inputs, const float* __restrict__ state,
    const float* __restrict__ Wxz, const float* __restrict__ Whz, const float* __restrict__ bz,
    const float* __restrict__ Wxr, const float* __restrict__ Whr, const float* __restrict__ br,
    const float* __restrict__ Wxh, const float* __restrict__ Whh, const float* __restrict__ bh,
    const float* __restrict__ Whq, const float* __restrict__ bhq,
    float* __restrict__ out, char* __restrict__ ws) {

    unsigned* arr = (unsigned*)(ws + OFF_BAR);          // 16 x 64B
    unsigned* epw = (unsigned*)(ws + OFF_BAR + 1024);   // epoch broadcast word
    __bf16* WxzT = (__bf16*)(ws + OFF_WXZT);
    __bf16* WxrT = (__bf16*)(ws + OFF_WXRT);
    __bf16* WxhT = (__bf16*)(ws + OFF_WXHT);
    __bf16* WhzT = (__bf16*)(ws + OFF_WHZT);
    __bf16* WhrT = (__bf16*)(ws + OFF_WHRT);
    __bf16* WhhT = (__bf16*)(ws + OFF_WHHT);
    __bf16* WhqT = (__bf16*)(ws + OFF_WHQT);
    __bf16* Xbf  = (__bf16*)(ws + OFF_XBF);   // 2 x (64 x 1024)
    __bf16* Hbf  = (__bf16*)(ws + OFF_HBF);   // 2 x (64 x 2048)
    __bf16* RHbf = (__bf16*)(ws + OFF_RHBF);  // 64 x 2048

    __shared__ float red[2 * 4 * 64 * 20];    // 40 KB: Z-reduce | R-reduce

    const int b   = (int)blockIdx.x;
    const int tid = (int)threadIdx.x;
    const int gr  = tid >> 3;                 // output row this thread owns
    const int gc  = (tid & 7) << 1;           // output col (2 consecutive)
    unsigned ep = 0;

    // ---------------- prologue (all blocks) --------------------------------
    transpose_cvt(Wxz, WxzT, I_, 11);
    transpose_cvt(Wxr, WxrT, I_, 11);
    transpose_cvt(Wxh, WxhT, I_, 11);
    transpose_cvt(Whz, WhzT, H_, 11);
    transpose_cvt(Whr, WhrT, H_, 11);
    transpose_cvt(Whh, WhhT, H_, 11);
    transpose_cvt(Whq, WhqT, H_, 10);
    {
        int q = b * NTHREADS + tid;           // quad index
        if (q < B_ * I_ / 4) {
            f32x4 v = *(const f32x4*)(inputs + (size_t)q * 4);
            cstore8(Xbf + (size_t)q * 4, pack4bf(v[0], v[1], v[2], v[3]));
        }
        if (q < B_ * H_ / 4) {
            f32x4 v = *(const f32x4*)(state + (size_t)q * 4);
            cstore8(Hbf + (size_t)q * 4, pack4bf(v[0], v[1], v[2], v[3]));
        }
    }
    bar_arrive_fence(arr);
    bar_wait(arr, epw, ++ep);

    const int lane = tid & 63;
    const int w    = tid >> 6;
    const int l15  = lane & 15;
    const int q8   = (lane >> 4) << 3;

    if (b < 128) {
        // ================= GATE BLOCKS: Z,R,H~,H_new for 16 cols ==========
        const int c16 = b << 4;

        bf16x8 pbZ[12], pbR[12], pbHx[4], pbHh[8];
#pragma unroll
        for (int i = 0; i < 4; ++i)
            pbZ[i] = *(const bf16x8*)(WxzT + (size_t)(c16 + l15) * I_ + ((w + (i << 3)) << 5) + q8);
#pragma unroll
        for (int i = 0; i < 8; ++i)
            pbZ[4 + i] = *(const bf16x8*)(WhzT + (size_t)(c16 + l15) * H_ + ((w + (i << 3)) << 5) + q8);
#pragma unroll
        for (int i = 0; i < 4; ++i)
            pbR[i] = *(const bf16x8*)(WxrT + (size_t)(c16 + l15) * I_ + ((w + (i << 3)) << 5) + q8);
#pragma unroll
        for (int i = 0; i < 8; ++i)
            pbR[4 + i] = *(const bf16x8*)(WhrT + (size_t)(c16 + l15) * H_ + ((w + (i << 3)) << 5) + q8);
#pragma unroll
        for (int i = 0; i < 4; ++i)
            pbHx[i] = *(const bf16x8*)(WxhT + (size_t)(c16 + l15) * I_ + ((w + (i << 3)) << 5) + q8);
#pragma unroll
        for (int i = 0; i < 8; ++i)
            pbHh[i] = *(const bf16x8*)(WhhT + (size_t)(c16 + l15) * H_ + ((w + (i << 3)) << 5) + q8);

        // biases + register-resident H (f32) for the (row, 2 cols) this thread owns
        const float bz0 = bz[c16 + gc], bz1 = bz[c16 + gc + 1];
        const float br0 = br[c16 + gc], br1 = br[c16 + gc + 1];
        const float bh0 = bh[c16 + gc], bh1 = bh[c16 + gc + 1];
        float hreg[2];
        {
            f32x2 v = *(const f32x2*)(state + (size_t)gr * H_ + c16 + gc);
            hreg[0] = v[0]; hreg[1] = v[1];
        }

        for (int t = 0; t < T_; ++t) {
            const int cur = t & 1, nxt = cur ^ 1;
            const __bf16* Xc = Xbf + (size_t)cur * B_ * I_;
            const __bf16* Hc = Hbf + (size_t)cur * B_ * H_;

            // ---- phase A: fused Z | R | H~ X-part ----
            f32x4 accH[4];
#pragma unroll
            for (int m = 0; m < 4; ++m) accH[m] = f32x4{0.f, 0.f, 0.f, 0.f};
            float zsum[2], rsum[2];
            gate_phaseA(Xc, Hc, pbZ, pbR, pbHx, accH, red, zsum, rsum);

            const float z0 = fsigmoid(zsum[0] + bz0);
            const float z1 = fsigmoid(zsum[1] + bz1);
            bf16x2 h2 = *(const bf16x2*)(Hc + (size_t)gr * H_ + c16 + gc);
            const float rh0 = fsigmoid(rsum[0] + br0) * (float)h2[0];
            const float rh1 = fsigmoid(rsum[1] + br1) * (float)h2[1];
            cstore4(RHbf + (size_t)gr * H_ + c16 + gc, pack2bf(rh0, rh1));

            bar_arrive(arr);
            bar_wait(arr, epw, ++ep);

            // ---- phase B: H~ RH-part, H_new ----
            gemm_accN<8, 0>(RHbf, H_, pbHh, accH);
            float o2[2];
            gemm_reduce(accH, red, o2);
            const float ht0 = ftanh(o2[0] + bh0);
            const float ht1 = ftanh(o2[1] + bh1);
            const float hn0 = z0 * hreg[0] + (1.0f - z0) * ht0;
            const float hn1 = z1 * hreg[1] + (1.0f - z1) * ht1;
            hreg[0] = hn0; hreg[1] = hn1;
            cstore4(Hbf + (size_t)nxt * B_ * H_ + (size_t)gr * H_ + c16 + gc,
                    pack2bf(hn0, hn1));
            if (t == T_ - 1) {
                f32x2 v; v[0] = hn0; v[1] = hn1;
                *(f32x2*)(out + (size_t)T_ * B_ * I_ + (size_t)gr * H_ + c16 + gc) = v;
            }
            bar_arrive(arr);
            bar_wait(arr, epw, ++ep);
        }
    } else if (b < 192) {
        // ================= Y BLOCKS: Y = H @ Whq for 16 cols ==============
        const int yc = (b - 128) << 4;
        bf16x8 pbY[8];
#pragma unroll
        for (int i = 0; i < 8; ++i)
            pbY[i] = *(const bf16x8*)(WhqT + (size_t)(yc + l15) * H_ + ((w + (i << 3)) << 5) + q8);
        const float bq0 = bhq[yc + gc], bq1 = bhq[yc + gc + 1];

        for (int t = 0; t < T_; ++t) {
            const int cur = t & 1;
            const __bf16* Hc = Hbf + (size_t)cur * B_ * H_;

            bar_arrive(arr);                      // no phase-A work
            if (t > 0) {                          // barrier-1 overlap window
                f32x4 acc[4];
#pragma unroll
                for (int m = 0; m < 4; ++m) acc[m] = f32x4{0.f, 0.f, 0.f, 0.f};
                gemm_accN<8, 0>(Hc, H_, pbY, acc);
                float o2[2];
                gemm_reduce(acc, red, o2);
                f32x2 v;
                v[0] = o2[0] + bq0;
                v[1] = o2[1] + bq1;
                *(f32x2*)(out + ((size_t)(t - 1) * B_ + gr) * I_ + yc + gc) = v;
            }
            bar_wait(arr, epw, ++ep);

            bar_arrive(arr);                      // no phase-B work
            bar_wait(arr, epw, ++ep);
        }

        // epilogue: Y_{T-1} (H_T lives in slot (T_ & 1) == 0)
        {
            f32x4 acc[4];
#pragma unroll
            for (int m = 0; m < 4; ++m) acc[m] = f32x4{0.f, 0.f, 0.f, 0.f};
            gemm_accN<8, 0>(Hbf, H_, pbY, acc);
            float o2[2];
            gemm_reduce(acc, red, o2);
            f32x2 v;
            v[0] = o2[0] + bq0;
            v[1] = o2[1] + bq1;
            *(f32x2*)(out + ((size_t)(T_ - 1) * B_ + gr) * I_ + yc + gc) = v;
        }
    } else {
        // ================= CONV BLOCKS: X_{t+1} f32 -> bf16 ===============
        for (int t = 0; t < T_; ++t) {
            const int nxt = (t & 1) ^ 1;

            bar_arrive(arr);                      // no phase-A work
            if (t + 1 < T_ && tid < 256) {        // barrier-1 overlap window
                const int idx = (((b - 192) << 8) + tid) << 2;
                f32x4 v = *(const f32x4*)(inputs + (size_t)(t + 1) * B_ * I_ + idx);
                cstore8(Xbf + (size_t)nxt * B_ * I_ + idx,
                        pack4bf(v[0], v[1], v[2], v[3]));
            }
            bar_wait(arr, epw, ++ep);

            bar_arrive(arr);                      // no phase-B work
            bar_wait(arr, epw, ++ep);
        }
    }
}

extern "C" void kernel_launch(void* const* d_in, const int* in_sizes, int n_in,
                              void* d_out, int out_size, void* d_ws, size_t ws_size,
                              hipStream_t stream) {
    if (ws_size < WS_NEEDED) return;  // ~41.5 MB scratch required

    const float* inputs = (const float*)d_in[0];
    const float* state  = (const float*)d_in[1];
    const float* Wxz    = (const float*)d_in[2];
    const float* Whz    = (const float*)d_in[3];
    const float* bz     = (const float*)d_in[4];
    const float* Wxr    = (const float*)d_in[5];
    const float* Whr    = (const float*)d_in[6];
    const float* br     = (const float*)d_in[7];
    const float* Wxh    = (const float*)d_in[8];
    const float* Whh    = (const float*)d_in[9];
    const float* bh     = (const float*)d_in[10];
    const float* Whq    = (const float*)d_in[11];
    const float* bhq    = (const float*)d_in[12];

    hipMemsetAsync(d_ws, 0, 2048, stream);  // arrival counters + epoch word
    gru_persistent<<<NB, NTHREADS, 0, stream>>>(
        inputs, state, Wxz, Whz, bz, Wxr, Whr, br, Wxh, Whh, bh, Whq, bhq,
        (float*)d_out, (char*)d_ws);
}

// Round 5
// 16355.450 us; speedup vs baseline: 1.1449x; 1.1449x over previous
//
#include <hip/hip_runtime.h>
#include <cstdint>
#include <cstddef>

// ---------------------------------------------------------------------------
// GRU persistent kernel, round 7: round-5 partition + unlocked VGPR budget
// + deeper A-load pipeline.
//   - round 6's gate fusion REGRESSED (latency concentration) -> reverted to
//     the round-5 partition (Z|R split, Y/conv in barrier-1 window).
//   - VGPR_Count was pinned at 128 across rounds despite ~200 live values:
//     compiler occupancy heuristic was spilling the "pinned" weights. A
//     512-thread block at 1 block/CU is 2 waves/SIMD no matter what, so 256
//     VGPR/thread is free: __launch_bounds__(512,2) + amdgpu_waves_per_eu(2,2).
//   - phase GEMM pipeline deepened 3->5 (12-seg) / 3->4 (8-seg): 20 A-loads
//     in flight per wave to cover post-buffer_inv LLC latency.
//   - round-5 single-detector broadcast barrier kept verbatim (proven).
// ---------------------------------------------------------------------------

#define T_ 512
#define B_ 64
#define I_ 1024
#define H_ 2048
#define NB 256
#define NTHREADS 512
#define GSTRIDE (NB * NTHREADS)

typedef __attribute__((ext_vector_type(8))) __bf16 bf16x8;
typedef __attribute__((ext_vector_type(2))) __bf16 bf16x2;
typedef __attribute__((ext_vector_type(4))) float f32x4;
typedef __attribute__((ext_vector_type(2))) float f32x2;

// ---- workspace layout (bytes) ----
// barrier region: arr = 16 counters x 64B [0..1023]; epoch word @1024.
static constexpr size_t OFF_BAR  = 0;
static constexpr size_t OFF_WXZT = 3072;
static constexpr size_t SZ_WXT   = (size_t)H_ * I_ * 2;    // 4 MiB
static constexpr size_t SZ_WHT   = (size_t)H_ * H_ * 2;    // 8 MiB
static constexpr size_t OFF_WXRT = OFF_WXZT + SZ_WXT;
static constexpr size_t OFF_WXHT = OFF_WXRT + SZ_WXT;
static constexpr size_t OFF_WHZT = OFF_WXHT + SZ_WXT;
static constexpr size_t OFF_WHRT = OFF_WHZT + SZ_WHT;
static constexpr size_t OFF_WHHT = OFF_WHRT + SZ_WHT;
static constexpr size_t OFF_WHQT = OFF_WHHT + SZ_WHT;      // N=1024,K=2048
static constexpr size_t OFF_XBF  = OFF_WHQT + SZ_WXT;
static constexpr size_t OFF_HBF  = OFF_XBF + (size_t)2 * B_ * I_ * 2;
static constexpr size_t OFF_RHBF = OFF_HBF + (size_t)2 * B_ * H_ * 2;
static constexpr size_t WS_NEEDED = OFF_RHBF + (size_t)B_ * H_ * 2;

__device__ __forceinline__ float fsigmoid(float x) { return 1.0f / (1.0f + __expf(-x)); }
__device__ __forceinline__ float ftanh(float x)    { return 2.0f / (1.0f + __expf(-2.0f * x)) - 1.0f; }

// ---- coherent (sc1 write-through) stores for cross-block data ----
__device__ __forceinline__ void cstore8(void* p, unsigned long long v) {
    __hip_atomic_store((unsigned long long*)p, v, __ATOMIC_RELAXED, __HIP_MEMORY_SCOPE_AGENT);
}
__device__ __forceinline__ void cstore4(void* p, unsigned v) {
    __hip_atomic_store((unsigned*)p, v, __ATOMIC_RELAXED, __HIP_MEMORY_SCOPE_AGENT);
}
__device__ __forceinline__ unsigned long long pack4bf(float a, float b, float c, float d) {
    union { unsigned short s[4]; unsigned long long u; } x;
    union { __bf16 b; unsigned short s; } t;
    t.b = (__bf16)a; x.s[0] = t.s;
    t.b = (__bf16)b; x.s[1] = t.s;
    t.b = (__bf16)c; x.s[2] = t.s;
    t.b = (__bf16)d; x.s[3] = t.s;
    return x.u;
}
__device__ __forceinline__ unsigned pack2bf(float a, float b) {
    union { unsigned short s[2]; unsigned u; } x;
    union { __bf16 b; unsigned short s; } t;
    t.b = (__bf16)a; x.s[0] = t.s;
    t.b = (__bf16)b; x.s[1] = t.s;
    return x.u;
}

// ---- barrier: arrive ------------------------------------------------------
__device__ __forceinline__ void bar_arrive(unsigned* arr) {
    __syncthreads();   // drains vmcnt -> this block's WT stores are globally visible
    if (threadIdx.x == 0)
        __hip_atomic_fetch_add(&arr[(blockIdx.x & 15) * 16], 1u,
                               __ATOMIC_RELAXED, __HIP_MEMORY_SCOPE_AGENT);
}

__device__ __forceinline__ void bar_arrive_fence(unsigned* arr) {
    __syncthreads();
    __threadfence();   // prologue only: flush write-back transpose stores
    if (threadIdx.x == 0)
        __hip_atomic_fetch_add(&arr[(blockIdx.x & 15) * 16], 1u,
                               __ATOMIC_RELAXED, __HIP_MEMORY_SCOPE_AGENT);
}

__device__ __forceinline__ unsigned arr_sum(unsigned* arr) {
    unsigned sum = 0;
#pragma unroll
    for (int g = 0; g < 16; ++g)
        sum += __hip_atomic_load(&arr[g * 16],
                                 __ATOMIC_RELAXED, __HIP_MEMORY_SCOPE_AGENT);
    return sum;
}

// ---- barrier: wait (detector broadcast) -----------------------------------
__device__ __forceinline__ void bar_wait(unsigned* arr, unsigned* epw, unsigned ep) {
    if (threadIdx.x == 0) {
        const unsigned want = ep * (unsigned)NB;
        if (blockIdx.x == NB - 1) {
            // sole poller of the arrival counters
            while (arr_sum(arr) < want)
                __builtin_amdgcn_s_sleep(1);
            __hip_atomic_store(epw, ep, __ATOMIC_RELAXED, __HIP_MEMORY_SCOPE_AGENT);
        } else {
            // read-only poll on one dedicated LLC line
            int spins = 0;
            for (;;) {
                if (__hip_atomic_load(epw, __ATOMIC_RELAXED,
                                      __HIP_MEMORY_SCOPE_AGENT) >= ep) break;
                if ((++spins & 2047) == 0 && arr_sum(arr) >= want) break;  // insurance
                __builtin_amdgcn_s_sleep(1);
            }
        }
        // acquire: one cache-inv so subsequent normal loads see fresh data
        (void)__hip_atomic_load(&arr[0], __ATOMIC_ACQUIRE, __HIP_MEMORY_SCOPE_AGENT);
    }
    __syncthreads();
    asm volatile("" ::: "memory");
}

// f32 (K x N row-major) -> bf16 transposed (N x K row-major), normal stores
__device__ __forceinline__ void transpose_cvt(const float* __restrict__ src,
                                              __bf16* __restrict__ dst,
                                              int K, int lgN) {
    const int N = 1 << lgN;
    const int total = K << lgN;
    for (int idx = (int)(blockIdx.x * blockDim.x + threadIdx.x); idx < total; idx += GSTRIDE) {
        int k = idx >> lgN;
        int n = idx & (N - 1);
        dst[(size_t)n * K + k] = (__bf16)src[idx];
    }
}

// ---------------------------------------------------------------------------
// GEMM pieces with REGISTER-RESIDENT B. Tile = 64 rows x 16 cols.
// Wave w, segment i covers kb = (w + i*8)*32 within A's K dim (stride ks).
// pbw[OFF+i] is the matching pinned weight fragment. PIPE-deep A pipeline.
// ---------------------------------------------------------------------------
template<int NSEG, int OFF, int N>
__device__ __forceinline__ void gemm_accN(const __bf16* __restrict__ A, int ks,
                                          const bf16x8 (&pbw)[N], f32x4 acc[4]) {
    static_assert(OFF + NSEG <= N, "weight frags");
    constexpr int PIPE = 4;
    const int tid  = (int)threadIdx.x;
    const int lane = tid & 63;
    const int w    = tid >> 6;
    const int l15  = lane & 15;
    const int q8   = (lane >> 4) << 3;

    bf16x8 pa[PIPE][4];
    auto lseg = [&](int i, int s) {
        const int kb = ((w + (i << 3)) << 5) + q8;
#pragma unroll
        for (int m = 0; m < 4; ++m)
            pa[s][m] = *(const bf16x8*)(A + (size_t)((m << 4) + l15) * ks + kb);
    };

    lseg(0, 0);
    if constexpr (NSEG > 1) lseg(1, 1);
    if constexpr (NSEG > 2) lseg(2, 2);
    if constexpr (NSEG > 3) lseg(3, 3);
#pragma unroll
    for (int i = 0; i < NSEG; ++i) {
        const int s = i % PIPE;
#pragma unroll
        for (int m = 0; m < 4; ++m)
            acc[m] = __builtin_amdgcn_mfma_f32_16x16x32_bf16(pa[s][m], pbw[OFF + i], acc[m], 0, 0, 0);
        if (i + PIPE < NSEG) lseg(i + PIPE, s);
    }
}

// cross-wave reduction through LDS (64x16 tile, pitch 20)
__device__ __forceinline__ void gemm_reduce(f32x4 acc[4], float* __restrict__ red,
                                            float out2[2]) {
    constexpr int RP = 20;
    const int tid  = (int)threadIdx.x;
    const int lane = tid & 63;
    const int w    = tid >> 6;
    const int l15  = lane & 15;
    const int q4   = (lane >> 4) << 2;

    if (w >= 4) {
        float* rw = red + (size_t)(w - 4) * (64 * RP);
#pragma unroll
        for (int m = 0; m < 4; ++m)
#pragma unroll
            for (int r = 0; r < 4; ++r)
                rw[((m << 4) + q4 + r) * RP + l15] = acc[m][r];
    }
    __syncthreads();
    if (w < 4) {
        float* rw = red + (size_t)w * (64 * RP);
#pragma unroll
        for (int m = 0; m < 4; ++m)
#pragma unroll
            for (int r = 0; r < 4; ++r)
                rw[((m << 4) + q4 + r) * RP + l15] += acc[m][r];
    }
    __syncthreads();
    {
        const int a = (tid >> 3) * RP + ((tid & 7) << 1);
        f32x2 s0 = *(const f32x2*)(red + a);
        f32x2 s1 = *(const f32x2*)(red + 64 * RP + a);
        f32x2 s2 = *(const f32x2*)(red + 2 * 64 * RP + a);
        f32x2 s3 = *(const f32x2*)(red + 3 * 64 * RP + a);
        f32x2 s = s0 + s1 + s2 + s3;
        out2[0] = s[0]; out2[1] = s[1];
    }
}

// combined 12-segment pipeline for phase A (X then H without drain), 5-deep
template<int IX, int IH, int N>
__device__ __forceinline__ void gemm_reg(
    const __bf16* __restrict__ Ax, const __bf16* __restrict__ Ah,
    const bf16x8 (&pbw)[N], float* __restrict__ red, float out2[2])
{
    constexpr int ITER = IX + IH;
    constexpr int PIPE = 5;
    static_assert(ITER <= N, "weight frags");
    const int tid  = (int)threadIdx.x;
    const int lane = tid & 63;
    const int w    = tid >> 6;
    const int l15  = lane & 15;
    const int q8   = (lane >> 4) << 3;

    f32x4 acc[4];
#pragma unroll
    for (int m = 0; m < 4; ++m) acc[m] = f32x4{0.f, 0.f, 0.f, 0.f};

    bf16x8 pa[PIPE][4];
    auto lseg = [&](int i, int s) {
        const bool isx = (i < IX);
        const __bf16* A = isx ? Ax : Ah;
        const int ks = isx ? I_ : H_;
        const int kb = (isx ? ((w + (i << 3)) << 5)
                            : ((w + ((i - IX) << 3)) << 5)) + q8;
#pragma unroll
        for (int m = 0; m < 4; ++m)
            pa[s][m] = *(const bf16x8*)(A + (size_t)((m << 4) + l15) * ks + kb);
    };

    lseg(0, 0);
    if constexpr (ITER > 1) lseg(1, 1);
    if constexpr (ITER > 2) lseg(2, 2);
    if constexpr (ITER > 3) lseg(3, 3);
    if constexpr (ITER > 4) lseg(4, 4);
#pragma unroll
    for (int i = 0; i < ITER; ++i) {
        const int s = i % PIPE;
#pragma unroll
        for (int m = 0; m < 4; ++m)
            acc[m] = __builtin_amdgcn_mfma_f32_16x16x32_bf16(pa[s][m], pbw[i], acc[m], 0, 0, 0);
        if (i + PIPE < ITER) lseg(i + PIPE, s);
    }
    gemm_reduce(acc, red, out2);
}

__global__ __launch_bounds__(NTHREADS, 2)
__attribute__((amdgpu_waves_per_eu(2, 2)))
void gru_persistent(
    const float* __restrict__ inputs, const float* __restrict__ state,
    const float* __restrict__ Wxz, const float* __restrict__ Whz, const float* __restrict__ bz,
    const float* __restrict__ Wxr, const float* __restrict__ Whr, const float* __restrict__ br,
    const float* __restrict__ Wxh, const float* __restrict__ Whh, const float* __restrict__ bh,
    const float* __restrict__ Whq, const float* __restrict__ bhq,
    float* __restrict__ out, char* __restrict__ ws) {

    unsigned* arr = (unsigned*)(ws + OFF_BAR);          // 16 x 64B
    unsigned* epw = (unsigned*)(ws + OFF_BAR + 1024);   // epoch broadcast word
    __bf16* WxzT = (__bf16*)(ws + OFF_WXZT);
    __bf16* WxrT = (__bf16*)(ws + OFF_WXRT);
    __bf16* WxhT = (__bf16*)(ws + OFF_WXHT);
    __bf16* WhzT = (__bf16*)(ws + OFF_WHZT);
    __bf16* WhrT = (__bf16*)(ws + OFF_WHRT);
    __bf16* WhhT = (__bf16*)(ws + OFF_WHHT);
    __bf16* WhqT = (__bf16*)(ws + OFF_WHQT);
    __bf16* Xbf  = (__bf16*)(ws + OFF_XBF);   // 2 x (64 x 1024)
    __bf16* Hbf  = (__bf16*)(ws + OFF_HBF);   // 2 x (64 x 2048)
    __bf16* RHbf = (__bf16*)(ws + OFF_RHBF);  // 64 x 2048

    __shared__ float red[4 * 64 * 20];        // 20 KB reduction scratch

    const int b   = (int)blockIdx.x;
    const int tid = (int)threadIdx.x;
    const int c16 = (b & 127) << 4;           // col base (Z cols b<128, R cols else)
    const int gr  = tid >> 3;                 // output row this thread owns
    const int gc  = (tid & 7) << 1;           // output col (2 consecutive)
    unsigned ep = 0;

    // ---------------- prologue ---------------------------------------------
    transpose_cvt(Wxz, WxzT, I_, 11);
    transpose_cvt(Wxr, WxrT, I_, 11);
    transpose_cvt(Wxh, WxhT, I_, 11);
    transpose_cvt(Whz, WhzT, H_, 11);
    transpose_cvt(Whr, WhrT, H_, 11);
    transpose_cvt(Whh, WhhT, H_, 11);
    transpose_cvt(Whq, WhqT, H_, 10);
    {
        int q = b * NTHREADS + tid;           // quad index
        if (q < B_ * I_ / 4) {
            f32x4 v = *(const f32x4*)(inputs + (size_t)q * 4);
            cstore8(Xbf + (size_t)q * 4, pack4bf(v[0], v[1], v[2], v[3]));
        }
        if (q < B_ * H_ / 4) {
            f32x4 v = *(const f32x4*)(state + (size_t)q * 4);
            cstore8(Hbf + (size_t)q * 4, pack4bf(v[0], v[1], v[2], v[3]));
        }
    }

    // register-resident H (f32) and Z for the 2 cols x row this thread owns
    float hreg[2] = {0.f, 0.f};
    float zreg[2] = {0.f, 0.f};
    if (b < 128) {
        f32x2 v = *(const f32x2*)(state + (size_t)gr * H_ + c16 + gc);
        hreg[0] = v[0]; hreg[1] = v[1];
    }
    bar_arrive_fence(arr);
    bar_wait(arr, epw, ++ep);

    // ---------------- pin weight slices in registers (once) ----------------
    const int lane = tid & 63;
    const int w    = tid >> 6;
    const int l15  = lane & 15;
    const int q8   = (lane >> 4) << 3;

    bf16x8 pbA[12];   // phase-A weights: Wxz|Whz (b<128) or Wxr|Whr (b>=128)
    bf16x8 pbB[12];   // phase-B weights: Wxh|Whh (b<128) or Whq[0..7] (128<=b<192)
    if (b < 128) {
#pragma unroll
        for (int i = 0; i < 4; ++i)
            pbA[i] = *(const bf16x8*)(WxzT + (size_t)(c16 + l15) * I_ + ((w + (i << 3)) << 5) + q8);
#pragma unroll
        for (int i = 0; i < 8; ++i)
            pbA[4 + i] = *(const bf16x8*)(WhzT + (size_t)(c16 + l15) * H_ + ((w + (i << 3)) << 5) + q8);
#pragma unroll
        for (int i = 0; i < 4; ++i)
            pbB[i] = *(const bf16x8*)(WxhT + (size_t)(c16 + l15) * I_ + ((w + (i << 3)) << 5) + q8);
#pragma unroll
        for (int i = 0; i < 8; ++i)
            pbB[4 + i] = *(const bf16x8*)(WhhT + (size_t)(c16 + l15) * H_ + ((w + (i << 3)) << 5) + q8);
    } else {
#pragma unroll
        for (int i = 0; i < 4; ++i)
            pbA[i] = *(const bf16x8*)(WxrT + (size_t)(c16 + l15) * I_ + ((w + (i << 3)) << 5) + q8);
#pragma unroll
        for (int i = 0; i < 8; ++i)
            pbA[4 + i] = *(const bf16x8*)(WhrT + (size_t)(c16 + l15) * H_ + ((w + (i << 3)) << 5) + q8);
        if (b < 192) {
            const int yc = (b - 128) << 4;
#pragma unroll
            for (int i = 0; i < 8; ++i)
                pbB[i] = *(const bf16x8*)(WhqT + (size_t)(yc + l15) * H_ + ((w + (i << 3)) << 5) + q8);
        }
    }

    // ---------------- main recurrence --------------------------------------
    for (int t = 0; t < T_; ++t) {
        const int cur = t & 1, nxt = cur ^ 1;
        const __bf16* Xc = Xbf + (size_t)cur * B_ * I_;
        const __bf16* Hc = Hbf + (size_t)cur * B_ * H_;
        float o2[2];

        // ---- phase A: Z (blocks 0..127) / R,RH (blocks 128..255) ----
        if (b < 128) {
            gemm_reg<4, 8>(Xc, Hc, pbA, red, o2);
            zreg[0] = fsigmoid(o2[0] + bz[c16 + gc]);
            zreg[1] = fsigmoid(o2[1] + bz[c16 + gc + 1]);
        } else {
            gemm_reg<4, 8>(Xc, Hc, pbA, red, o2);
            bf16x2 h2 = *(const bf16x2*)(Hc + (size_t)gr * H_ + c16 + gc);
            float rh0 = fsigmoid(o2[0] + br[c16 + gc])     * (float)h2[0];
            float rh1 = fsigmoid(o2[1] + br[c16 + gc + 1]) * (float)h2[1];
            cstore4(RHbf + (size_t)gr * H_ + c16 + gc, pack2bf(rh0, rh1));
        }
        bar_arrive(arr);

        // ---- overlapped with barrier-1 wait (no dependency on RH) ----
        f32x4 accB[4];
#pragma unroll
        for (int m = 0; m < 4; ++m) accB[m] = f32x4{0.f, 0.f, 0.f, 0.f};
        if (b < 128) {
            // X-part of the H~ GEMM: depends only on Xc (already published)
            gemm_accN<4, 0>(Xc, I_, pbB, accB);
        } else if (b < 192) {
            // entire Y_{t-1} GEMM: depends only on Hc (already published)
            if (t > 0) {
                const int yc = (b - 128) << 4;
                gemm_accN<8, 0>(Hc, H_, pbB, accB);
                gemm_reduce(accB, red, o2);
                f32x2 v;
                v[0] = o2[0] + bhq[yc + gc];
                v[1] = o2[1] + bhq[yc + gc + 1];
                *(f32x2*)(out + ((size_t)(t - 1) * B_ + gr) * I_ + yc + gc) = v;
            }
        } else {
            // X_{t+1} conversion: depends only on global inputs
            if (t + 1 < T_ && tid < 256) {
                const int idx = (((b - 192) << 8) + tid) << 2;
                f32x4 v = *(const f32x4*)(inputs + (size_t)(t + 1) * B_ * I_ + idx);
                cstore8(Xbf + (size_t)nxt * B_ * I_ + idx,
                        pack4bf(v[0], v[1], v[2], v[3]));
            }
        }
        bar_wait(arr, epw, ++ep);

        // ---- phase B completion: H-part of H~, then H_new ----
        if (b < 128) {
            gemm_accN<8, 4>(RHbf, H_, pbB, accB);
            gemm_reduce(accB, red, o2);
            float ht0 = ftanh(o2[0] + bh[c16 + gc]);
            float ht1 = ftanh(o2[1] + bh[c16 + gc + 1]);
            float hn0 = zreg[0] * hreg[0] + (1.0f - zreg[0]) * ht0;
            float hn1 = zreg[1] * hreg[1] + (1.0f - zreg[1]) * ht1;
            hreg[0] = hn0; hreg[1] = hn1;
            cstore4(Hbf + (size_t)nxt * B_ * H_ + (size_t)gr * H_ + c16 + gc,
                    pack2bf(hn0, hn1));
            if (t == T_ - 1) {
                f32x2 v; v[0] = hn0; v[1] = hn1;
                *(f32x2*)(out + (size_t)T_ * B_ * I_ + (size_t)gr * H_ + c16 + gc) = v;
            }
        }
        bar_arrive(arr);
        bar_wait(arr, epw, ++ep);
    }

    // ---------------- epilogue: Y_{T-1} ------------------------------------
    if (b >= 128 && b < 192) {
        const __bf16* Hc = Hbf;   // slot (T_ & 1) == 0
        const int yc = (b - 128) << 4;
        f32x4 accB[4];
#pragma unroll
        for (int m = 0; m < 4; ++m) accB[m] = f32x4{0.f, 0.f, 0.f, 0.f};
        float o2[2];
        gemm_accN<8, 0>(Hc, H_, pbB, accB);
        gemm_reduce(accB, red, o2);
        f32x2 v;
        v[0] = o2[0] + bhq[yc + gc];
        v[1] = o2[1] + bhq[yc + gc + 1];
        *(f32x2*)(out + ((size_t)(T_ - 1) * B_ + gr) * I_ + yc + gc) = v;
    }
}

extern "C" void kernel_launch(void* const* d_in, const int* in_sizes, int n_in,
                              void* d_out, int out_size, void* d_ws, size_t ws_size,
                              hipStream_t stream) {
    if (ws_size < WS_NEEDED) return;  // ~41.5 MB scratch required

    const float* inputs = (const float*)d_in[0];
    const float* state  = (const float*)d_in[1];
    const float* Wxz    = (const float*)d_in[2];
    const float* Whz    = (const float*)d_in[3];
    const float* bz     = (const float*)d_in[4];
    const float* Wxr    = (const float*)d_in[5];
    const float* Whr    = (const float*)d_in[6];
    const float* br     = (const float*)d_in[7];
    const float* Wxh    = (const float*)d_in[8];
    const float* Whh    = (const float*)d_in[9];
    const float* bh     = (const float*)d_in[10];
    const float* Whq    = (const float*)d_in[11];
    const float* bhq    = (const float*)d_in[12];

    hipMemsetAsync(d_ws, 0, 2048, stream);  // arrival counters + epoch word
    gru_persistent<<<NB, NTHREADS, 0, stream>>>(
        inputs, state, Wxz, Whz, bz, Wxr, Whr, br, Wxh, Whh, bh, Whq, bhq,
        (float*)d_out, (char*)d_ws);
}

// Round 6
// 13006.500 us; speedup vs baseline: 1.4397x; 1.2575x over previous
//
#include <hip/hip_runtime.h>
#include <cstdint>
#include <cstddef>

// ---------------------------------------------------------------------------
// GRU persistent kernel, round 8: store-based arrivals + X-part off the
// critical path.
//   - barrier arrivals are now per-block epoch STORES to 256 dedicated 64B
//     lines (zero RMW serialization). Detector block (255) scans all slots
//     with 256 threads in parallel, broadcasts to 8 replicated epoch lines;
//     pollers read their blockIdx&7 replica (no single-line read storm).
//   - conv blocks publish X_{t+1} at barrier-1 (conversion moved BEFORE the
//     arrive); gate/R blocks pre-accumulate the 4 X-segments of the NEXT
//     step's phase-A GEMM inside barrier-2's arrive->wait window. Phase A
//     critical path shrinks 12 -> 8 segments.
//   - round-5 partition, register/AGPR-pinned weights, PIPE=4 kept.
// ---------------------------------------------------------------------------

#define T_ 512
#define B_ 64
#define I_ 1024
#define H_ 2048
#define NB 256
#define NTHREADS 512
#define GSTRIDE (NB * NTHREADS)

typedef __attribute__((ext_vector_type(8))) __bf16 bf16x8;
typedef __attribute__((ext_vector_type(2))) __bf16 bf16x2;
typedef __attribute__((ext_vector_type(4))) float f32x4;
typedef __attribute__((ext_vector_type(2))) float f32x2;

// ---- workspace layout (bytes) ----
// slots: 256 x 64B arrival lines [0..16383]; epw: 8 x 64B epoch replicas.
static constexpr size_t OFF_SLOT = 0;
static constexpr size_t OFF_EPW  = 16384;
static constexpr size_t OFF_WXZT = 20480;
static constexpr size_t SZ_WXT   = (size_t)H_ * I_ * 2;    // 4 MiB
static constexpr size_t SZ_WHT   = (size_t)H_ * H_ * 2;    // 8 MiB
static constexpr size_t OFF_WXRT = OFF_WXZT + SZ_WXT;
static constexpr size_t OFF_WXHT = OFF_WXRT + SZ_WXT;
static constexpr size_t OFF_WHZT = OFF_WXHT + SZ_WXT;
static constexpr size_t OFF_WHRT = OFF_WHZT + SZ_WHT;
static constexpr size_t OFF_WHHT = OFF_WHRT + SZ_WHT;
static constexpr size_t OFF_WHQT = OFF_WHHT + SZ_WHT;      // N=1024,K=2048
static constexpr size_t OFF_XBF  = OFF_WHQT + SZ_WXT;
static constexpr size_t OFF_HBF  = OFF_XBF + (size_t)2 * B_ * I_ * 2;
static constexpr size_t OFF_RHBF = OFF_HBF + (size_t)2 * B_ * H_ * 2;
static constexpr size_t WS_NEEDED = OFF_RHBF + (size_t)B_ * H_ * 2;

__device__ __forceinline__ float fsigmoid(float x) { return 1.0f / (1.0f + __expf(-x)); }
__device__ __forceinline__ float ftanh(float x)    { return 2.0f / (1.0f + __expf(-2.0f * x)) - 1.0f; }

// ---- coherent (sc1 write-through) stores for cross-block data ----
__device__ __forceinline__ void cstore8(void* p, unsigned long long v) {
    __hip_atomic_store((unsigned long long*)p, v, __ATOMIC_RELAXED, __HIP_MEMORY_SCOPE_AGENT);
}
__device__ __forceinline__ void cstore4(void* p, unsigned v) {
    __hip_atomic_store((unsigned*)p, v, __ATOMIC_RELAXED, __HIP_MEMORY_SCOPE_AGENT);
}
__device__ __forceinline__ unsigned long long pack4bf(float a, float b, float c, float d) {
    union { unsigned short s[4]; unsigned long long u; } x;
    union { __bf16 b; unsigned short s; } t;
    t.b = (__bf16)a; x.s[0] = t.s;
    t.b = (__bf16)b; x.s[1] = t.s;
    t.b = (__bf16)c; x.s[2] = t.s;
    t.b = (__bf16)d; x.s[3] = t.s;
    return x.u;
}
__device__ __forceinline__ unsigned pack2bf(float a, float b) {
    union { unsigned short s[2]; unsigned u; } x;
    union { __bf16 b; unsigned short s; } t;
    t.b = (__bf16)a; x.s[0] = t.s;
    t.b = (__bf16)b; x.s[1] = t.s;
    return x.u;
}

// ---- barrier: store-based arrive ------------------------------------------
__device__ __forceinline__ void bar_arrive(unsigned* slots, unsigned ep) {
    __syncthreads();   // drains vmcnt -> this block's WT stores are globally visible
    if (threadIdx.x == 0)
        __hip_atomic_store(&slots[blockIdx.x * 16], ep,
                           __ATOMIC_RELAXED, __HIP_MEMORY_SCOPE_AGENT);
}

__device__ __forceinline__ void bar_arrive_fence(unsigned* slots, unsigned ep) {
    __syncthreads();
    __threadfence();   // prologue only: flush write-back transpose stores
    if (threadIdx.x == 0)
        __hip_atomic_store(&slots[blockIdx.x * 16], ep,
                           __ATOMIC_RELAXED, __HIP_MEMORY_SCOPE_AGENT);
}

// ---- barrier: wait (parallel-scan detector, replicated broadcast) ---------
__device__ __forceinline__ void bar_wait(unsigned* slots, unsigned* epw, unsigned ep) {
    const int tid = (int)threadIdx.x;
    if (blockIdx.x == NB - 1) {
        // detector: 256 threads each watch one arrival slot
        if (tid < NB) {
            while (__hip_atomic_load(&slots[tid * 16], __ATOMIC_RELAXED,
                                     __HIP_MEMORY_SCOPE_AGENT) < ep)
                __builtin_amdgcn_s_sleep(1);
        }
        __syncthreads();
        if (tid < 8)
            __hip_atomic_store(&epw[tid * 16], ep,
                               __ATOMIC_RELAXED, __HIP_MEMORY_SCOPE_AGENT);
        if (tid == 0)
            (void)__hip_atomic_load(&slots[0], __ATOMIC_ACQUIRE, __HIP_MEMORY_SCOPE_AGENT);
    } else {
        if (tid == 0) {
            unsigned* p = &epw[(blockIdx.x & 7) * 16];
            while (__hip_atomic_load(p, __ATOMIC_RELAXED,
                                     __HIP_MEMORY_SCOPE_AGENT) < ep)
                __builtin_amdgcn_s_sleep(1);
            // acquire: one cache-inv so subsequent normal loads see fresh data
            (void)__hip_atomic_load(&slots[0], __ATOMIC_ACQUIRE, __HIP_MEMORY_SCOPE_AGENT);
        }
    }
    __syncthreads();
    asm volatile("" ::: "memory");
}

// f32 (K x N row-major) -> bf16 transposed (N x K row-major), normal stores
__device__ __forceinline__ void transpose_cvt(const float* __restrict__ src,
                                              __bf16* __restrict__ dst,
                                              int K, int lgN) {
    const int N = 1 << lgN;
    const int total = K << lgN;
    for (int idx = (int)(blockIdx.x * blockDim.x + threadIdx.x); idx < total; idx += GSTRIDE) {
        int k = idx >> lgN;
        int n = idx & (N - 1);
        dst[(size_t)n * K + k] = (__bf16)src[idx];
    }
}

// ---------------------------------------------------------------------------
// GEMM pieces with REGISTER-RESIDENT B. Tile = 64 rows x 16 cols.
// Wave w, segment i covers kb = (w + i*8)*32 within A's K dim (stride ks).
// pbw[OFF+i] is the matching pinned weight fragment. PIPE-deep A pipeline.
// ---------------------------------------------------------------------------
template<int NSEG, int OFF, int N>
__device__ __forceinline__ void gemm_accN(const __bf16* __restrict__ A, int ks,
                                          const bf16x8 (&pbw)[N], f32x4 acc[4]) {
    static_assert(OFF + NSEG <= N, "weight frags");
    constexpr int PIPE = 4;
    const int tid  = (int)threadIdx.x;
    const int lane = tid & 63;
    const int w    = tid >> 6;
    const int l15  = lane & 15;
    const int q8   = (lane >> 4) << 3;

    bf16x8 pa[PIPE][4];
    auto lseg = [&](int i, int s) {
        const int kb = ((w + (i << 3)) << 5) + q8;
#pragma unroll
        for (int m = 0; m < 4; ++m)
            pa[s][m] = *(const bf16x8*)(A + (size_t)((m << 4) + l15) * ks + kb);
    };

    lseg(0, 0);
    if constexpr (NSEG > 1) lseg(1, 1);
    if constexpr (NSEG > 2) lseg(2, 2);
    if constexpr (NSEG > 3) lseg(3, 3);
#pragma unroll
    for (int i = 0; i < NSEG; ++i) {
        const int s = i % PIPE;
#pragma unroll
        for (int m = 0; m < 4; ++m)
            acc[m] = __builtin_amdgcn_mfma_f32_16x16x32_bf16(pa[s][m], pbw[OFF + i], acc[m], 0, 0, 0);
        if (i + PIPE < NSEG) lseg(i + PIPE, s);
    }
}

// cross-wave reduction through LDS (64x16 tile, pitch 20)
__device__ __forceinline__ void gemm_reduce(f32x4 acc[4], float* __restrict__ red,
                                            float out2[2]) {
    constexpr int RP = 20;
    const int tid  = (int)threadIdx.x;
    const int lane = tid & 63;
    const int w    = tid >> 6;
    const int l15  = lane & 15;
    const int q4   = (lane >> 4) << 2;

    if (w >= 4) {
        float* rw = red + (size_t)(w - 4) * (64 * RP);
#pragma unroll
        for (int m = 0; m < 4; ++m)
#pragma unroll
            for (int r = 0; r < 4; ++r)
                rw[((m << 4) + q4 + r) * RP + l15] = acc[m][r];
    }
    __syncthreads();
    if (w < 4) {
        float* rw = red + (size_t)w * (64 * RP);
#pragma unroll
        for (int m = 0; m < 4; ++m)
#pragma unroll
            for (int r = 0; r < 4; ++r)
                rw[((m << 4) + q4 + r) * RP + l15] += acc[m][r];
    }
    __syncthreads();
    {
        const int a = (tid >> 3) * RP + ((tid & 7) << 1);
        f32x2 s0 = *(const f32x2*)(red + a);
        f32x2 s1 = *(const f32x2*)(red + 64 * RP + a);
        f32x2 s2 = *(const f32x2*)(red + 2 * 64 * RP + a);
        f32x2 s3 = *(const f32x2*)(red + 3 * 64 * RP + a);
        f32x2 s = s0 + s1 + s2 + s3;
        out2[0] = s[0]; out2[1] = s[1];
    }
}

__global__ __launch_bounds__(NTHREADS, 2)
__attribute__((amdgpu_waves_per_eu(2, 2)))
void gru_persistent(
    const float* __restrict__ inputs, const float* __restrict__ state,
    const float* __restrict__ Wxz, const float* __restrict__ Whz, const float* __restrict__ bz,
    const float* __restrict__ Wxr, const float* __restrict__ Whr, const float* __restrict__ br,
    const float* __restrict__ Wxh, const float* __restrict__ Whh, const float* __restrict__ bh,
    const float* __restrict__ Whq, const float* __restrict__ bhq,
    float* __restrict__ out, char* __restrict__ ws) {

    unsigned* slots = (unsigned*)(ws + OFF_SLOT);   // 256 x 64B
    unsigned* epw   = (unsigned*)(ws + OFF_EPW);    // 8 x 64B replicas
    __bf16* WxzT = (__bf16*)(ws + OFF_WXZT);
    __bf16* WxrT = (__bf16*)(ws + OFF_WXRT);
    __bf16* WxhT = (__bf16*)(ws + OFF_WXHT);
    __bf16* WhzT = (__bf16*)(ws + OFF_WHZT);
    __bf16* WhrT = (__bf16*)(ws + OFF_WHRT);
    __bf16* WhhT = (__bf16*)(ws + OFF_WHHT);
    __bf16* WhqT = (__bf16*)(ws + OFF_WHQT);
    __bf16* Xbf  = (__bf16*)(ws + OFF_XBF);   // 2 x (64 x 1024)
    __bf16* Hbf  = (__bf16*)(ws + OFF_HBF);   // 2 x (64 x 2048)
    __bf16* RHbf = (__bf16*)(ws + OFF_RHBF);  // 64 x 2048

    __shared__ float red[4 * 64 * 20];        // 20 KB reduction scratch

    const int b   = (int)blockIdx.x;
    const int tid = (int)threadIdx.x;
    const int c16 = (b & 127) << 4;           // col base (Z cols b<128, R cols else)
    const int gr  = tid >> 3;                 // output row this thread owns
    const int gc  = (tid & 7) << 1;           // output col (2 consecutive)
    unsigned ep = 0;

    // ---------------- prologue ---------------------------------------------
    transpose_cvt(Wxz, WxzT, I_, 11);
    transpose_cvt(Wxr, WxrT, I_, 11);
    transpose_cvt(Wxh, WxhT, I_, 11);
    transpose_cvt(Whz, WhzT, H_, 11);
    transpose_cvt(Whr, WhrT, H_, 11);
    transpose_cvt(Whh, WhhT, H_, 11);
    transpose_cvt(Whq, WhqT, H_, 10);
    {
        int q = b * NTHREADS + tid;           // quad index
        if (q < B_ * I_ / 4) {
            f32x4 v = *(const f32x4*)(inputs + (size_t)q * 4);
            cstore8(Xbf + (size_t)q * 4, pack4bf(v[0], v[1], v[2], v[3]));
        }
        if (q < B_ * H_ / 4) {
            f32x4 v = *(const f32x4*)(state + (size_t)q * 4);
            cstore8(Hbf + (size_t)q * 4, pack4bf(v[0], v[1], v[2], v[3]));
        }
    }
    ++ep;
    bar_arrive_fence(slots, ep);
    bar_wait(slots, epw, ep);

    const int lane = tid & 63;
    const int w    = tid >> 6;
    const int l15  = lane & 15;
    const int q8   = (lane >> 4) << 3;

    if (b < 128) {
        // ============ GATE (Z) BLOCKS: Z, H~, H_new for 16 cols ============
        bf16x8 pbA[12];   // Wxz | Whz
        bf16x8 pbB[12];   // Wxh | Whh
#pragma unroll
        for (int i = 0; i < 4; ++i)
            pbA[i] = *(const bf16x8*)(WxzT + (size_t)(c16 + l15) * I_ + ((w + (i << 3)) << 5) + q8);
#pragma unroll
        for (int i = 0; i < 8; ++i)
            pbA[4 + i] = *(const bf16x8*)(WhzT + (size_t)(c16 + l15) * H_ + ((w + (i << 3)) << 5) + q8);
#pragma unroll
        for (int i = 0; i < 4; ++i)
            pbB[i] = *(const bf16x8*)(WxhT + (size_t)(c16 + l15) * I_ + ((w + (i << 3)) << 5) + q8);
#pragma unroll
        for (int i = 0; i < 8; ++i)
            pbB[4 + i] = *(const bf16x8*)(WhhT + (size_t)(c16 + l15) * H_ + ((w + (i << 3)) << 5) + q8);

        const float bz0 = bz[c16 + gc], bz1 = bz[c16 + gc + 1];
        const float bh0 = bh[c16 + gc], bh1 = bh[c16 + gc + 1];
        float hreg[2];
        {
            f32x2 v = *(const f32x2*)(state + (size_t)gr * H_ + c16 + gc);
            hreg[0] = v[0]; hreg[1] = v[1];
        }

        // prefetch X-part of phase A for t=0 (X_0 published at prologue bar)
        f32x4 accA[4];
#pragma unroll
        for (int m = 0; m < 4; ++m) accA[m] = f32x4{0.f, 0.f, 0.f, 0.f};
        gemm_accN<4, 0>(Xbf, I_, pbA, accA);

        for (int t = 0; t < T_; ++t) {
            const int cur = t & 1, nxt = cur ^ 1;
            const __bf16* Xc = Xbf + (size_t)cur * B_ * I_;
            const __bf16* Hc = Hbf + (size_t)cur * B_ * H_;
            float o2[2];

            // ---- phase A: finish Z with the 8 H-segments ----
            gemm_accN<8, 4>(Hc, H_, pbA, accA);
            gemm_reduce(accA, red, o2);
            const float z0 = fsigmoid(o2[0] + bz0);
            const float z1 = fsigmoid(o2[1] + bz1);
            ++ep;
            bar_arrive(slots, ep);

            // ---- barrier-1 window: H~ X-part (depends only on Xc) ----
            f32x4 accB[4];
#pragma unroll
            for (int m = 0; m < 4; ++m) accB[m] = f32x4{0.f, 0.f, 0.f, 0.f};
            gemm_accN<4, 0>(Xc, I_, pbB, accB);
            bar_wait(slots, epw, ep);

            // ---- phase B: H~ RH-part, H_new ----
            gemm_accN<8, 4>(RHbf, H_, pbB, accB);
            gemm_reduce(accB, red, o2);
            const float ht0 = ftanh(o2[0] + bh0);
            const float ht1 = ftanh(o2[1] + bh1);
            const float hn0 = z0 * hreg[0] + (1.0f - z0) * ht0;
            const float hn1 = z1 * hreg[1] + (1.0f - z1) * ht1;
            hreg[0] = hn0; hreg[1] = hn1;
            cstore4(Hbf + (size_t)nxt * B_ * H_ + (size_t)gr * H_ + c16 + gc,
                    pack2bf(hn0, hn1));
            if (t == T_ - 1) {
                f32x2 v; v[0] = hn0; v[1] = hn1;
                *(f32x2*)(out + (size_t)T_ * B_ * I_ + (size_t)gr * H_ + c16 + gc) = v;
            }
            ++ep;
            bar_arrive(slots, ep);

            // ---- barrier-2 window: prefetch next step's Z X-part ----
#pragma unroll
            for (int m = 0; m < 4; ++m) accA[m] = f32x4{0.f, 0.f, 0.f, 0.f};
            if (t + 1 < T_)
                gemm_accN<4, 0>(Xbf + (size_t)nxt * B_ * I_, I_, pbA, accA);
            bar_wait(slots, epw, ep);
        }
    } else if (b < 192) {
        // ============ R + Y BLOCKS: R,RH (phase A) + Y (window 1) ==========
        bf16x8 pbA[12];   // Wxr | Whr
        bf16x8 pbY[8];    // Whq
#pragma unroll
        for (int i = 0; i < 4; ++i)
            pbA[i] = *(const bf16x8*)(WxrT + (size_t)(c16 + l15) * I_ + ((w + (i << 3)) << 5) + q8);
#pragma unroll
        for (int i = 0; i < 8; ++i)
            pbA[4 + i] = *(const bf16x8*)(WhrT + (size_t)(c16 + l15) * H_ + ((w + (i << 3)) << 5) + q8);
        const int yc = (b - 128) << 4;
#pragma unroll
        for (int i = 0; i < 8; ++i)
            pbY[i] = *(const bf16x8*)(WhqT + (size_t)(yc + l15) * H_ + ((w + (i << 3)) << 5) + q8);
        const float br0 = br[c16 + gc], br1 = br[c16 + gc + 1];
        const float bq0 = bhq[yc + gc], bq1 = bhq[yc + gc + 1];

        f32x4 accA[4];
#pragma unroll
        for (int m = 0; m < 4; ++m) accA[m] = f32x4{0.f, 0.f, 0.f, 0.f};
        gemm_accN<4, 0>(Xbf, I_, pbA, accA);

        for (int t = 0; t < T_; ++t) {
            const int cur = t & 1, nxt = cur ^ 1;
            const __bf16* Hc = Hbf + (size_t)cur * B_ * H_;
            float o2[2];

            // ---- phase A: finish R with the 8 H-segments; publish RH ----
            gemm_accN<8, 4>(Hc, H_, pbA, accA);
            gemm_reduce(accA, red, o2);
            bf16x2 h2 = *(const bf16x2*)(Hc + (size_t)gr * H_ + c16 + gc);
            const float rh0 = fsigmoid(o2[0] + br0) * (float)h2[0];
            const float rh1 = fsigmoid(o2[1] + br1) * (float)h2[1];
            cstore4(RHbf + (size_t)gr * H_ + c16 + gc, pack2bf(rh0, rh1));
            ++ep;
            bar_arrive(slots, ep);

            // ---- barrier-1 window: Y_{t-1} (depends only on Hc) ----
            if (t > 0) {
                f32x4 accY[4];
#pragma unroll
                for (int m = 0; m < 4; ++m) accY[m] = f32x4{0.f, 0.f, 0.f, 0.f};
                gemm_accN<8, 0>(Hc, H_, pbY, accY);
                gemm_reduce(accY, red, o2);
                f32x2 v;
                v[0] = o2[0] + bq0;
                v[1] = o2[1] + bq1;
                *(f32x2*)(out + ((size_t)(t - 1) * B_ + gr) * I_ + yc + gc) = v;
            }
            bar_wait(slots, epw, ep);

            // ---- phase B: none ----
            ++ep;
            bar_arrive(slots, ep);

            // ---- barrier-2 window: prefetch next step's R X-part ----
#pragma unroll
            for (int m = 0; m < 4; ++m) accA[m] = f32x4{0.f, 0.f, 0.f, 0.f};
            if (t + 1 < T_)
                gemm_accN<4, 0>(Xbf + (size_t)nxt * B_ * I_, I_, pbA, accA);
            bar_wait(slots, epw, ep);
        }

        // epilogue: Y_{T-1} (H_T lives in slot (T_ & 1) == 0)
        {
            f32x4 accY[4];
#pragma unroll
            for (int m = 0; m < 4; ++m) accY[m] = f32x4{0.f, 0.f, 0.f, 0.f};
            float o2[2];
            gemm_accN<8, 0>(Hbf, H_, pbY, accY);
            gemm_reduce(accY, red, o2);
            f32x2 v;
            v[0] = o2[0] + bq0;
            v[1] = o2[1] + bq1;
            *(f32x2*)(out + ((size_t)(T_ - 1) * B_ + gr) * I_ + yc + gc) = v;
        }
    } else {
        // ============ R + CONV BLOCKS: R,RH (phase A) + X conversion =======
        bf16x8 pbA[12];   // Wxr | Whr
#pragma unroll
        for (int i = 0; i < 4; ++i)
            pbA[i] = *(const bf16x8*)(WxrT + (size_t)(c16 + l15) * I_ + ((w + (i << 3)) << 5) + q8);
#pragma unroll
        for (int i = 0; i < 8; ++i)
            pbA[4 + i] = *(const bf16x8*)(WhrT + (size_t)(c16 + l15) * H_ + ((w + (i << 3)) << 5) + q8);
        const float br0 = br[c16 + gc], br1 = br[c16 + gc + 1];

        f32x4 accA[4];
#pragma unroll
        for (int m = 0; m < 4; ++m) accA[m] = f32x4{0.f, 0.f, 0.f, 0.f};
        gemm_accN<4, 0>(Xbf, I_, pbA, accA);

        for (int t = 0; t < T_; ++t) {
            const int cur = t & 1, nxt = cur ^ 1;
            const __bf16* Hc = Hbf + (size_t)cur * B_ * H_;
            float o2[2];

            // ---- phase A: X_{t+1} conversion FIRST (publishes at bar-1),
            //      then finish R with the 8 H-segments ----
            if (t + 1 < T_ && tid < 256) {
                const int idx = (((b - 192) << 8) + tid) << 2;
                f32x4 v = *(const f32x4*)(inputs + (size_t)(t + 1) * B_ * I_ + idx);
                cstore8(Xbf + (size_t)nxt * B_ * I_ + idx,
                        pack4bf(v[0], v[1], v[2], v[3]));
            }
            gemm_accN<8, 4>(Hc, H_, pbA, accA);
            gemm_reduce(accA, red, o2);
            bf16x2 h2 = *(const bf16x2*)(Hc + (size_t)gr * H_ + c16 + gc);
            const float rh0 = fsigmoid(o2[0] + br0) * (float)h2[0];
            const float rh1 = fsigmoid(o2[1] + br1) * (float)h2[1];
            cstore4(RHbf + (size_t)gr * H_ + c16 + gc, pack2bf(rh0, rh1));
            ++ep;
            bar_arrive(slots, ep);
            bar_wait(slots, epw, ep);

            // ---- phase B: none ----
            ++ep;
            bar_arrive(slots, ep);

            // ---- barrier-2 window: prefetch next step's R X-part ----
#pragma unroll
            for (int m = 0; m < 4; ++m) accA[m] = f32x4{0.f, 0.f, 0.f, 0.f};
            if (t + 1 < T_)
                gemm_accN<4, 0>(Xbf + (size_t)nxt * B_ * I_, I_, pbA, accA);
            bar_wait(slots, epw, ep);
        }
    }
}

extern "C" void kernel_launch(void* const* d_in, const int* in_sizes, int n_in,
                              void* d_out, int out_size, void* d_ws, size_t ws_size,
                              hipStream_t stream) {
    if (ws_size < WS_NEEDED) return;  // ~41.5 MB scratch required

    const float* inputs = (const float*)d_in[0];
    const float* state  = (const float*)d_in[1];
    const float* Wxz    = (const float*)d_in[2];
    const float* Whz    = (const float*)d_in[3];
    const float* bz     = (const float*)d_in[4];
    const float* Wxr    = (const float*)d_in[5];
    const float* Whr    = (const float*)d_in[6];
    const float* br     = (const float*)d_in[7];
    const float* Wxh    = (const float*)d_in[8];
    const float* Whh    = (const float*)d_in[9];
    const float* bh     = (const float*)d_in[10];
    const float* Whq    = (const float*)d_in[11];
    const float* bhq    = (const float*)d_in[12];

    hipMemsetAsync(d_ws, 0, 20480, stream);  // arrival slots + epoch replicas
    gru_persistent<<<NB, NTHREADS, 0, stream>>>(
        inputs, state, Wxz, Whz, bz, Wxr, Whr, br, Wxh, Whh, bh, Whq, bhq,
        (float*)d_out, (char*)d_ws);
}

// Round 7
// 11449.763 us; speedup vs baseline: 1.6355x; 1.1360x over previous
//
#include <hip/hip_runtime.h>
#include <cstdint>
#include <cstddef>

// ---------------------------------------------------------------------------
// GRU persistent kernel, round 9: ONE grid barrier per step + producer flags.
//   - bar-1 (RH publication) removed: R-blocks set 128 per-producer epoch
//     flags after a __syncthreads drain; gate blocks poll them directly
//     (tid<128, one flag each) + one acquire. Detection = 1 LLC round trip
//     instead of arrive->detector->broadcast->poll.
//   - X_{t+1} published via 64 conv-block flags (set mid-step, polled in the
//     post-arrive window where they're long set; correctness-only).
//   - single end-of-step grid barrier (R8's store-arrival + parallel-scan
//     detector + replicated broadcast, verbatim). WAR hazards: Xbf/Hbf are
//     double-buffered; RHbf's next write is separated from this step's reads
//     by the end-of-step barrier.
//   - R8 partition, pinned weights, PIPE=4, windowed X-prefetches kept.
// ---------------------------------------------------------------------------

#define T_ 512
#define B_ 64
#define I_ 1024
#define H_ 2048
#define NB 256
#define NTHREADS 512
#define GSTRIDE (NB * NTHREADS)

typedef __attribute__((ext_vector_type(8))) __bf16 bf16x8;
typedef __attribute__((ext_vector_type(2))) __bf16 bf16x2;
typedef __attribute__((ext_vector_type(4))) float f32x4;
typedef __attribute__((ext_vector_type(2))) float f32x2;

// ---- workspace layout (bytes) ----
// slots: 256 x 64B end-of-step arrival lines
// epw  : 8 x 64B epoch broadcast replicas
// rhf  : 128 x 64B RH producer flags (value = t+1)
// xf   : 64 x 64B X producer flags (value = t+1)
static constexpr size_t OFF_SLOT = 0;
static constexpr size_t OFF_EPW  = 16384;
static constexpr size_t OFF_RHF  = 17408;
static constexpr size_t OFF_XF   = 25600;
static constexpr size_t OFF_WXZT = 32768;
static constexpr size_t SZ_WXT   = (size_t)H_ * I_ * 2;    // 4 MiB
static constexpr size_t SZ_WHT   = (size_t)H_ * H_ * 2;    // 8 MiB
static constexpr size_t OFF_WXRT = OFF_WXZT + SZ_WXT;
static constexpr size_t OFF_WXHT = OFF_WXRT + SZ_WXT;
static constexpr size_t OFF_WHZT = OFF_WXHT + SZ_WXT;
static constexpr size_t OFF_WHRT = OFF_WHZT + SZ_WHT;
static constexpr size_t OFF_WHHT = OFF_WHRT + SZ_WHT;
static constexpr size_t OFF_WHQT = OFF_WHHT + SZ_WHT;      // N=1024,K=2048
static constexpr size_t OFF_XBF  = OFF_WHQT + SZ_WXT;
static constexpr size_t OFF_HBF  = OFF_XBF + (size_t)2 * B_ * I_ * 2;
static constexpr size_t OFF_RHBF = OFF_HBF + (size_t)2 * B_ * H_ * 2;
static constexpr size_t WS_NEEDED = OFF_RHBF + (size_t)B_ * H_ * 2;

__device__ __forceinline__ float fsigmoid(float x) { return 1.0f / (1.0f + __expf(-x)); }
__device__ __forceinline__ float ftanh(float x)    { return 2.0f / (1.0f + __expf(-2.0f * x)) - 1.0f; }

// ---- coherent (sc1 write-through) stores for cross-block data ----
__device__ __forceinline__ void cstore8(void* p, unsigned long long v) {
    __hip_atomic_store((unsigned long long*)p, v, __ATOMIC_RELAXED, __HIP_MEMORY_SCOPE_AGENT);
}
__device__ __forceinline__ void cstore4(void* p, unsigned v) {
    __hip_atomic_store((unsigned*)p, v, __ATOMIC_RELAXED, __HIP_MEMORY_SCOPE_AGENT);
}
__device__ __forceinline__ unsigned long long pack4bf(float a, float b, float c, float d) {
    union { unsigned short s[4]; unsigned long long u; } x;
    union { __bf16 b; unsigned short s; } t;
    t.b = (__bf16)a; x.s[0] = t.s;
    t.b = (__bf16)b; x.s[1] = t.s;
    t.b = (__bf16)c; x.s[2] = t.s;
    t.b = (__bf16)d; x.s[3] = t.s;
    return x.u;
}
__device__ __forceinline__ unsigned pack2bf(float a, float b) {
    union { unsigned short s[2]; unsigned u; } x;
    union { __bf16 b; unsigned short s; } t;
    t.b = (__bf16)a; x.s[0] = t.s;
    t.b = (__bf16)b; x.s[1] = t.s;
    return x.u;
}

// ---- end-of-step barrier: store-based arrive ------------------------------
__device__ __forceinline__ void bar_arrive(unsigned* slots, unsigned ep) {
    __syncthreads();   // drains vmcnt -> this block's WT stores are globally visible
    if (threadIdx.x == 0)
        __hip_atomic_store(&slots[blockIdx.x * 16], ep,
                           __ATOMIC_RELAXED, __HIP_MEMORY_SCOPE_AGENT);
}

__device__ __forceinline__ void bar_arrive_fence(unsigned* slots, unsigned ep) {
    __syncthreads();
    __threadfence();   // prologue only: flush write-back transpose stores
    if (threadIdx.x == 0)
        __hip_atomic_store(&slots[blockIdx.x * 16], ep,
                           __ATOMIC_RELAXED, __HIP_MEMORY_SCOPE_AGENT);
}

// ---- end-of-step barrier: wait (parallel-scan detector, replicated bc) ----
__device__ __forceinline__ void bar_wait(unsigned* slots, unsigned* epw, unsigned ep) {
    const int tid = (int)threadIdx.x;
    if (blockIdx.x == NB - 1) {
        // detector: 256 threads each watch one arrival slot
        if (tid < NB) {
            while (__hip_atomic_load(&slots[tid * 16], __ATOMIC_RELAXED,
                                     __HIP_MEMORY_SCOPE_AGENT) < ep)
                __builtin_amdgcn_s_sleep(1);
        }
        __syncthreads();
        if (tid < 8)
            __hip_atomic_store(&epw[tid * 16], ep,
                               __ATOMIC_RELAXED, __HIP_MEMORY_SCOPE_AGENT);
        if (tid == 0)
            (void)__hip_atomic_load(&slots[0], __ATOMIC_ACQUIRE, __HIP_MEMORY_SCOPE_AGENT);
    } else {
        if (tid == 0) {
            unsigned* p = &epw[(blockIdx.x & 7) * 16];
            while (__hip_atomic_load(p, __ATOMIC_RELAXED,
                                     __HIP_MEMORY_SCOPE_AGENT) < ep)
                __builtin_amdgcn_s_sleep(1);
            (void)__hip_atomic_load(&slots[0], __ATOMIC_ACQUIRE, __HIP_MEMORY_SCOPE_AGENT);
        }
    }
    __syncthreads();
    asm volatile("" ::: "memory");
}

// ---- producer-flag wait: NFLAGS flags must reach `want` -------------------
template<int NFLAGS>
__device__ __forceinline__ void flag_wait(unsigned* flags, unsigned want) {
    const int tid = (int)threadIdx.x;
    if (tid < NFLAGS) {
        while (__hip_atomic_load(&flags[tid * 16], __ATOMIC_RELAXED,
                                 __HIP_MEMORY_SCOPE_AGENT) < want)
            __builtin_amdgcn_s_sleep(1);
    }
    __syncthreads();
    if (tid == 0)
        (void)__hip_atomic_load(&flags[0], __ATOMIC_ACQUIRE, __HIP_MEMORY_SCOPE_AGENT);
    __syncthreads();
    asm volatile("" ::: "memory");
}

// f32 (K x N row-major) -> bf16 transposed (N x K row-major), normal stores
__device__ __forceinline__ void transpose_cvt(const float* __restrict__ src,
                                              __bf16* __restrict__ dst,
                                              int K, int lgN) {
    const int N = 1 << lgN;
    const int total = K << lgN;
    for (int idx = (int)(blockIdx.x * blockDim.x + threadIdx.x); idx < total; idx += GSTRIDE) {
        int k = idx >> lgN;
        int n = idx & (N - 1);
        dst[(size_t)n * K + k] = (__bf16)src[idx];
    }
}

// ---------------------------------------------------------------------------
// GEMM pieces with REGISTER-RESIDENT B. Tile = 64 rows x 16 cols.
// Wave w, segment i covers kb = (w + i*8)*32 within A's K dim (stride ks).
// pbw[OFF+i] is the matching pinned weight fragment. PIPE=4-deep A pipeline.
// ---------------------------------------------------------------------------
template<int NSEG, int OFF, int N>
__device__ __forceinline__ void gemm_accN(const __bf16* __restrict__ A, int ks,
                                          const bf16x8 (&pbw)[N], f32x4 acc[4]) {
    static_assert(OFF + NSEG <= N, "weight frags");
    constexpr int PIPE = 4;
    const int tid  = (int)threadIdx.x;
    const int lane = tid & 63;
    const int w    = tid >> 6;
    const int l15  = lane & 15;
    const int q8   = (lane >> 4) << 3;

    bf16x8 pa[PIPE][4];
    auto lseg = [&](int i, int s) {
        const int kb = ((w + (i << 3)) << 5) + q8;
#pragma unroll
        for (int m = 0; m < 4; ++m)
            pa[s][m] = *(const bf16x8*)(A + (size_t)((m << 4) + l15) * ks + kb);
    };

    lseg(0, 0);
    if constexpr (NSEG > 1) lseg(1, 1);
    if constexpr (NSEG > 2) lseg(2, 2);
    if constexpr (NSEG > 3) lseg(3, 3);
#pragma unroll
    for (int i = 0; i < NSEG; ++i) {
        const int s = i % PIPE;
#pragma unroll
        for (int m = 0; m < 4; ++m)
            acc[m] = __builtin_amdgcn_mfma_f32_16x16x32_bf16(pa[s][m], pbw[OFF + i], acc[m], 0, 0, 0);
        if (i + PIPE < NSEG) lseg(i + PIPE, s);
    }
}

// cross-wave reduction through LDS (64x16 tile, pitch 20)
__device__ __forceinline__ void gemm_reduce(f32x4 acc[4], float* __restrict__ red,
                                            float out2[2]) {
    constexpr int RP = 20;
    const int tid  = (int)threadIdx.x;
    const int lane = tid & 63;
    const int w    = tid >> 6;
    const int l15  = lane & 15;
    const int q4   = (lane >> 4) << 2;

    if (w >= 4) {
        float* rw = red + (size_t)(w - 4) * (64 * RP);
#pragma unroll
        for (int m = 0; m < 4; ++m)
#pragma unroll
            for (int r = 0; r < 4; ++r)
                rw[((m << 4) + q4 + r) * RP + l15] = acc[m][r];
    }
    __syncthreads();
    if (w < 4) {
        float* rw = red + (size_t)w * (64 * RP);
#pragma unroll
        for (int m = 0; m < 4; ++m)
#pragma unroll
            for (int r = 0; r < 4; ++r)
                rw[((m << 4) + q4 + r) * RP + l15] += acc[m][r];
    }
    __syncthreads();
    {
        const int a = (tid >> 3) * RP + ((tid & 7) << 1);
        f32x2 s0 = *(const f32x2*)(red + a);
        f32x2 s1 = *(const f32x2*)(red + 64 * RP + a);
        f32x2 s2 = *(const f32x2*)(red + 2 * 64 * RP + a);
        f32x2 s3 = *(const f32x2*)(red + 3 * 64 * RP + a);
        f32x2 s = s0 + s1 + s2 + s3;
        out2[0] = s[0]; out2[1] = s[1];
    }
}

__global__ __launch_bounds__(NTHREADS, 2)
__attribute__((amdgpu_waves_per_eu(2, 2)))
void gru_persistent(
    const float* __restrict__ inputs, const float* __restrict__ state,
    const float* __restrict__ Wxz, const float* __restrict__ Whz, const float* __restrict__ bz,
    const float* __restrict__ Wxr, const float* __restrict__ Whr, const float* __restrict__ br,
    const float* __restrict__ Wxh, const float* __restrict__ Whh, const float* __restrict__ bh,
    const float* __restrict__ Whq, const float* __restrict__ bhq,
    float* __restrict__ out, char* __restrict__ ws) {

    unsigned* slots = (unsigned*)(ws + OFF_SLOT);   // 256 x 64B
    unsigned* epw   = (unsigned*)(ws + OFF_EPW);    // 8 x 64B replicas
    unsigned* rhf   = (unsigned*)(ws + OFF_RHF);    // 128 x 64B RH flags
    unsigned* xf    = (unsigned*)(ws + OFF_XF);     // 64 x 64B X flags
    __bf16* WxzT = (__bf16*)(ws + OFF_WXZT);
    __bf16* WxrT = (__bf16*)(ws + OFF_WXRT);
    __bf16* WxhT = (__bf16*)(ws + OFF_WXHT);
    __bf16* WhzT = (__bf16*)(ws + OFF_WHZT);
    __bf16* WhrT = (__bf16*)(ws + OFF_WHRT);
    __bf16* WhhT = (__bf16*)(ws + OFF_WHHT);
    __bf16* WhqT = (__bf16*)(ws + OFF_WHQT);
    __bf16* Xbf  = (__bf16*)(ws + OFF_XBF);   // 2 x (64 x 1024)
    __bf16* Hbf  = (__bf16*)(ws + OFF_HBF);   // 2 x (64 x 2048)
    __bf16* RHbf = (__bf16*)(ws + OFF_RHBF);  // 64 x 2048

    __shared__ float red[4 * 64 * 20];        // 20 KB reduction scratch

    const int b   = (int)blockIdx.x;
    const int tid = (int)threadIdx.x;
    const int c16 = (b & 127) << 4;           // col base (Z cols b<128, R cols else)
    const int gr  = tid >> 3;                 // output row this thread owns
    const int gc  = (tid & 7) << 1;           // output col (2 consecutive)
    unsigned ep = 0;

    // ---------------- prologue ---------------------------------------------
    transpose_cvt(Wxz, WxzT, I_, 11);
    transpose_cvt(Wxr, WxrT, I_, 11);
    transpose_cvt(Wxh, WxhT, I_, 11);
    transpose_cvt(Whz, WhzT, H_, 11);
    transpose_cvt(Whr, WhrT, H_, 11);
    transpose_cvt(Whh, WhhT, H_, 11);
    transpose_cvt(Whq, WhqT, H_, 10);
    {
        int q = b * NTHREADS + tid;           // quad index
        if (q < B_ * I_ / 4) {
            f32x4 v = *(const f32x4*)(inputs + (size_t)q * 4);
            cstore8(Xbf + (size_t)q * 4, pack4bf(v[0], v[1], v[2], v[3]));
        }
        if (q < B_ * H_ / 4) {
            f32x4 v = *(const f32x4*)(state + (size_t)q * 4);
            cstore8(Hbf + (size_t)q * 4, pack4bf(v[0], v[1], v[2], v[3]));
        }
    }
    ++ep;
    bar_arrive_fence(slots, ep);
    bar_wait(slots, epw, ep);

    const int lane = tid & 63;
    const int w    = tid >> 6;
    const int l15  = lane & 15;
    const int q8   = (lane >> 4) << 3;

    if (b < 128) {
        // ======== GATE (Z) BLOCKS: Z, H~, H_new for 16 cols ================
        bf16x8 pbA[12];   // Wxz | Whz
        bf16x8 pbB[12];   // Wxh | Whh
#pragma unroll
        for (int i = 0; i < 4; ++i)
            pbA[i] = *(const bf16x8*)(WxzT + (size_t)(c16 + l15) * I_ + ((w + (i << 3)) << 5) + q8);
#pragma unroll
        for (int i = 0; i < 8; ++i)
            pbA[4 + i] = *(const bf16x8*)(WhzT + (size_t)(c16 + l15) * H_ + ((w + (i << 3)) << 5) + q8);
#pragma unroll
        for (int i = 0; i < 4; ++i)
            pbB[i] = *(const bf16x8*)(WxhT + (size_t)(c16 + l15) * I_ + ((w + (i << 3)) << 5) + q8);
#pragma unroll
        for (int i = 0; i < 8; ++i)
            pbB[4 + i] = *(const bf16x8*)(WhhT + (size_t)(c16 + l15) * H_ + ((w + (i << 3)) << 5) + q8);

        const float bz0 = bz[c16 + gc], bz1 = bz[c16 + gc + 1];
        const float bh0 = bh[c16 + gc], bh1 = bh[c16 + gc + 1];
        float hreg[2];
        {
            f32x2 v = *(const f32x2*)(state + (size_t)gr * H_ + c16 + gc);
            hreg[0] = v[0]; hreg[1] = v[1];
        }

        // t=0 prefetch: X-parts of Z and H~ on X_0 (published at prologue)
        f32x4 accA[4], accB[4];
#pragma unroll
        for (int m = 0; m < 4; ++m) {
            accA[m] = f32x4{0.f, 0.f, 0.f, 0.f};
            accB[m] = f32x4{0.f, 0.f, 0.f, 0.f};
        }
        gemm_accN<4, 0>(Xbf, I_, pbA, accA);
        gemm_accN<4, 0>(Xbf, I_, pbB, accB);

        for (int t = 0; t < T_; ++t) {
            const int cur = t & 1, nxt = cur ^ 1;
            const __bf16* Hc = Hbf + (size_t)cur * B_ * H_;
            float o2[2];

            // ---- phase A: finish Z with 8 H-segments ----
            gemm_accN<8, 4>(Hc, H_, pbA, accA);
            gemm_reduce(accA, red, o2);
            const float z0 = fsigmoid(o2[0] + bz0);
            const float z1 = fsigmoid(o2[1] + bz1);

            // ---- wait for RH producers (128 flags), then phase B ----
            flag_wait<128>(rhf, (unsigned)(t + 1));
            gemm_accN<8, 4>(RHbf, H_, pbB, accB);
            gemm_reduce(accB, red, o2);
            const float ht0 = ftanh(o2[0] + bh0);
            const float ht1 = ftanh(o2[1] + bh1);
            const float hn0 = z0 * hreg[0] + (1.0f - z0) * ht0;
            const float hn1 = z1 * hreg[1] + (1.0f - z1) * ht1;
            hreg[0] = hn0; hreg[1] = hn1;
            cstore4(Hbf + (size_t)nxt * B_ * H_ + (size_t)gr * H_ + c16 + gc,
                    pack2bf(hn0, hn1));
            if (t == T_ - 1) {
                f32x2 v; v[0] = hn0; v[1] = hn1;
                *(f32x2*)(out + (size_t)T_ * B_ * I_ + (size_t)gr * H_ + c16 + gc) = v;
            }
            ++ep;
            bar_arrive(slots, ep);

            // ---- post-arrive window: prefetch next step's X-parts ----
#pragma unroll
            for (int m = 0; m < 4; ++m) {
                accA[m] = f32x4{0.f, 0.f, 0.f, 0.f};
                accB[m] = f32x4{0.f, 0.f, 0.f, 0.f};
            }
            if (t + 1 < T_) {
                flag_wait<64>(xf, (unsigned)(t + 1));
                gemm_accN<4, 0>(Xbf + (size_t)nxt * B_ * I_, I_, pbA, accA);
                gemm_accN<4, 0>(Xbf + (size_t)nxt * B_ * I_, I_, pbB, accB);
            }
            bar_wait(slots, epw, ep);
        }
    } else if (b < 192) {
        // ======== R + Y BLOCKS: R,RH then Y_{t-1} ==========================
        bf16x8 pbA[12];   // Wxr | Whr
        bf16x8 pbY[8];    // Whq
#pragma unroll
        for (int i = 0; i < 4; ++i)
            pbA[i] = *(const bf16x8*)(WxrT + (size_t)(c16 + l15) * I_ + ((w + (i << 3)) << 5) + q8);
#pragma unroll
        for (int i = 0; i < 8; ++i)
            pbA[4 + i] = *(const bf16x8*)(WhrT + (size_t)(c16 + l15) * H_ + ((w + (i << 3)) << 5) + q8);
        const int yc = (b - 128) << 4;
#pragma unroll
        for (int i = 0; i < 8; ++i)
            pbY[i] = *(const bf16x8*)(WhqT + (size_t)(yc + l15) * H_ + ((w + (i << 3)) << 5) + q8);
        const float br0 = br[c16 + gc], br1 = br[c16 + gc + 1];
        const float bq0 = bhq[yc + gc], bq1 = bhq[yc + gc + 1];

        f32x4 accA[4];
#pragma unroll
        for (int m = 0; m < 4; ++m) accA[m] = f32x4{0.f, 0.f, 0.f, 0.f};
        gemm_accN<4, 0>(Xbf, I_, pbA, accA);

        for (int t = 0; t < T_; ++t) {
            const int cur = t & 1, nxt = cur ^ 1;
            const __bf16* Hc = Hbf + (size_t)cur * B_ * H_;
            float o2[2];

            // ---- phase A: finish R with 8 H-segments; publish RH + flag ----
            gemm_accN<8, 4>(Hc, H_, pbA, accA);
            gemm_reduce(accA, red, o2);
            bf16x2 h2 = *(const bf16x2*)(Hc + (size_t)gr * H_ + c16 + gc);
            const float rh0 = fsigmoid(o2[0] + br0) * (float)h2[0];
            const float rh1 = fsigmoid(o2[1] + br1) * (float)h2[1];
            cstore4(RHbf + (size_t)gr * H_ + c16 + gc, pack2bf(rh0, rh1));
            __syncthreads();   // drain RH stores (per-wave vmcnt(0) at barrier)
            if (tid == 0)
                __hip_atomic_store(&rhf[(b - 128) * 16], (unsigned)(t + 1),
                                   __ATOMIC_RELAXED, __HIP_MEMORY_SCOPE_AGENT);

            // ---- Y_{t-1} (depends only on Hc, valid all step) ----
            if (t > 0) {
                f32x4 accY[4];
#pragma unroll
                for (int m = 0; m < 4; ++m) accY[m] = f32x4{0.f, 0.f, 0.f, 0.f};
                gemm_accN<8, 0>(Hc, H_, pbY, accY);
                gemm_reduce(accY, red, o2);
                f32x2 v;
                v[0] = o2[0] + bq0;
                v[1] = o2[1] + bq1;
                *(f32x2*)(out + ((size_t)(t - 1) * B_ + gr) * I_ + yc + gc) = v;
            }
            ++ep;
            bar_arrive(slots, ep);

            // ---- post-arrive window: prefetch next step's R X-part ----
#pragma unroll
            for (int m = 0; m < 4; ++m) accA[m] = f32x4{0.f, 0.f, 0.f, 0.f};
            if (t + 1 < T_) {
                flag_wait<64>(xf, (unsigned)(t + 1));
                gemm_accN<4, 0>(Xbf + (size_t)nxt * B_ * I_, I_, pbA, accA);
            }
            bar_wait(slots, epw, ep);
        }

        // epilogue: Y_{T-1} (H_T lives in slot (T_ & 1) == 0)
        {
            f32x4 accY[4];
#pragma unroll
            for (int m = 0; m < 4; ++m) accY[m] = f32x4{0.f, 0.f, 0.f, 0.f};
            float o2[2];
            gemm_accN<8, 0>(Hbf, H_, pbY, accY);
            gemm_reduce(accY, red, o2);
            f32x2 v;
            v[0] = o2[0] + bq0;
            v[1] = o2[1] + bq1;
            *(f32x2*)(out + ((size_t)(T_ - 1) * B_ + gr) * I_ + yc + gc) = v;
        }
    } else {
        // ======== R + CONV BLOCKS: X_{t+1} conversion + R,RH ===============
        bf16x8 pbA[12];   // Wxr | Whr
#pragma unroll
        for (int i = 0; i < 4; ++i)
            pbA[i] = *(const bf16x8*)(WxrT + (size_t)(c16 + l15) * I_ + ((w + (i << 3)) << 5) + q8);
#pragma unroll
        for (int i = 0; i < 8; ++i)
            pbA[4 + i] = *(const bf16x8*)(WhrT + (size_t)(c16 + l15) * H_ + ((w + (i << 3)) << 5) + q8);
        const float br0 = br[c16 + gc], br1 = br[c16 + gc + 1];

        f32x4 accA[4];
#pragma unroll
        for (int m = 0; m < 4; ++m) accA[m] = f32x4{0.f, 0.f, 0.f, 0.f};
        gemm_accN<4, 0>(Xbf, I_, pbA, accA);

        for (int t = 0; t < T_; ++t) {
            const int cur = t & 1, nxt = cur ^ 1;
            const __bf16* Hc = Hbf + (size_t)cur * B_ * H_;
            float o2[2];

            // ---- convert X_{t+1} FIRST (stores drained by reduce's sync) ----
            if (t + 1 < T_ && tid < 256) {
                const int idx = (((b - 192) << 8) + tid) << 2;
                f32x4 v = *(const f32x4*)(inputs + (size_t)(t + 1) * B_ * I_ + idx);
                cstore8(Xbf + (size_t)nxt * B_ * I_ + idx,
                        pack4bf(v[0], v[1], v[2], v[3]));
            }

            // ---- phase A: finish R with 8 H-segments; publish RH + flags ----
            gemm_accN<8, 4>(Hc, H_, pbA, accA);
            gemm_reduce(accA, red, o2);
            bf16x2 h2 = *(const bf16x2*)(Hc + (size_t)gr * H_ + c16 + gc);
            const float rh0 = fsigmoid(o2[0] + br0) * (float)h2[0];
            const float rh1 = fsigmoid(o2[1] + br1) * (float)h2[1];
            cstore4(RHbf + (size_t)gr * H_ + c16 + gc, pack2bf(rh0, rh1));
            __syncthreads();   // drain RH + X-conversion stores
            if (tid == 0) {
                __hip_atomic_store(&rhf[(b - 128) * 16], (unsigned)(t + 1),
                                   __ATOMIC_RELAXED, __HIP_MEMORY_SCOPE_AGENT);
                __hip_atomic_store(&xf[(b - 192) * 16], (unsigned)(t + 1),
                                   __ATOMIC_RELAXED, __HIP_MEMORY_SCOPE_AGENT);
            }
            ++ep;
            bar_arrive(slots, ep);

            // ---- post-arrive window: prefetch next step's R X-part ----
#pragma unroll
            for (int m = 0; m < 4; ++m) accA[m] = f32x4{0.f, 0.f, 0.f, 0.f};
            if (t + 1 < T_) {
                flag_wait<64>(xf, (unsigned)(t + 1));
                gemm_accN<4, 0>(Xbf + (size_t)nxt * B_ * I_, I_, pbA, accA);
            }
            bar_wait(slots, epw, ep);
        }
    }
}

extern "C" void kernel_launch(void* const* d_in, const int* in_sizes, int n_in,
                              void* d_out, int out_size, void* d_ws, size_t ws_size,
                              hipStream_t stream) {
    if (ws_size < WS_NEEDED) return;  // ~41.5 MB scratch required

    const float* inputs = (const float*)d_in[0];
    const float* state  = (const float*)d_in[1];
    const float* Wxz    = (const float*)d_in[2];
    const float* Whz    = (const float*)d_in[3];
    const float* bz     = (const float*)d_in[4];
    const float* Wxr    = (const float*)d_in[5];
    const float* Whr    = (const float*)d_in[6];
    const float* br     = (const float*)d_in[7];
    const float* Wxh    = (const float*)d_in[8];
    const float* Whh    = (const float*)d_in[9];
    const float* bh     = (const float*)d_in[10];
    const float* Whq    = (const float*)d_in[11];
    const float* bhq    = (const float*)d_in[12];

    hipMemsetAsync(d_ws, 0, 32768, stream);  // slots + epw + rhf + xf
    gru_persistent<<<NB, NTHREADS, 0, stream>>>(
        inputs, state, Wxz, Whz, bz, Wxr, Whr, br, Wxh, Whh, bh, Whq, bhq,
        (float*)d_out, (char*)d_ws);
}